// Round 4
// baseline (648.002 us; speedup 1.0000x reference)
//
#include <hip/hip_runtime.h>
#include <hip/hip_fp16.h>
#include <hip/hip_cooperative_groups.h>

namespace cg = cooperative_groups;

// GCN VGAE encoder:
//   h  = relu((A @ x) @ W1 + b1)          [associativity: A(xW) == (Ax)W]
//   mu = (A @ h) @ Wmu + bmu ; lv = (A @ h) @ Wlv + blv
// A = D^-1/2 (Adj + I) D^-1/2, deg on dst side. dinv folded into tables:
//   xs[s]=dinv_s*x[s]; hs[i]=dinv_i*relu(...); y_i = dinv_i*(sum_e xs[src]+xs[i])
//
// R15: build collapsed to 2 dispatches. R14 measured same-address global
// fetch-atomics at ~235ns each (serialized; 1.6M over 1568 addrs = 240us) --
// global-atomic designs are dead. R13 showed build bytes are irrelevant;
// cost is dispatch count (gaps + small-grid tails). So:
//  * coop_build (hipLaunchCooperativeKernel, 782x256): per-chunk bucket
//    histogram -> grid.sync -> per-bucket row scan (196 blocks, in-place)
//    -> grid.sync -> block-0 scan of bucket totals -> grid.sync -> scatter
//    with LDS cursors (R13's proven pattern). LDS atomics only.
//  * bucket_build fused with cast_scale: block holds its 512 nodes' dinv in
//    LDS; appends the coalesced xs cast. dinv global array deleted.
// Pipeline: coop_build -> bucket_build -> agg1 -> agg2 (was 9 dispatches).
// Aggs: exact R11 config (proven 56.6us each; gather plateau confirmed by 6
// failed configs at 1.27-2.0 TB/s).

#define BKT_SHIFT 9
#define BKT_NODES 512
#define CHUNK 2048

typedef __attribute__((ext_vector_type(8))) _Float16 half8;
typedef __attribute__((ext_vector_type(4))) float float4v;
typedef __attribute__((ext_vector_type(4))) unsigned uint4v;

__device__ __forceinline__ int imin(int a, int b) { return a < b ? a : b; }
__device__ __forceinline__ int imax(int a, int b) { return a > b ? a : b; }
__device__ __forceinline__ unsigned h2u(__half2 v) {
  union { __half2 h; unsigned u; } c; c.h = v; return c.u;
}
__device__ __forceinline__ __half2 u2h(unsigned x) {
  union { unsigned u; __half2 h; } c; c.u = x; return c.h;
}

// ---------------- cooperative build: count + scan + scatter ----------------
// cnt layout [bucket][chunk] (bucket-major). After Phase B1, cnt holds the
// within-row exclusive prefix; absolute offset = rowbase[bucket] + cnt[b][c].
// tmp entry packed: (src << 9) | (dst & 511)  [src < 2^17 for N=100k].
// Requires nblk <= 1024 (PER=4 row-scan) and nbk <= 256.
__global__ __launch_bounds__(256) void coop_build(const int* __restrict__ src,
                                                  const int* __restrict__ dst,
                                                  int* __restrict__ cnt,
                                                  int* __restrict__ rowsum,
                                                  int* __restrict__ rowbase,
                                                  int* __restrict__ tmp,
                                                  int E, int nbk, int nblk) {
  cg::grid_group grid = cg::this_grid();
  __shared__ int hist[2][256];
  __shared__ int red[256];
  __shared__ int cur[256];
  const int t = threadIdx.x;
  const int c = blockIdx.x;

  // ---- Phase A: per-chunk bucket histogram (dual sub-hist, int4 loads) ----
  const int h = (t >> 7) & 1;
  hist[0][t] = 0;
  hist[1][t] = 0;
  __syncthreads();
  const int base = c * CHUNK;
  const int end = imin(base + CHUNK, E);
  for (int e = base + t * 4; e < end; e += 1024) {
    if (e + 3 < end) {
      const int4 d4 = *(const int4*)(dst + e);
      atomicAdd(&hist[h][d4.x >> BKT_SHIFT], 1);
      atomicAdd(&hist[h][d4.y >> BKT_SHIFT], 1);
      atomicAdd(&hist[h][d4.z >> BKT_SHIFT], 1);
      atomicAdd(&hist[h][d4.w >> BKT_SHIFT], 1);
    } else {
      for (int k = e; k < end; ++k) atomicAdd(&hist[h][dst[k] >> BKT_SHIFT], 1);
    }
  }
  __syncthreads();
  if (t < nbk) cnt[t * nblk + c] = hist[0][t] + hist[1][t];
  __threadfence();
  grid.sync();

  // ---- Phase B1: blocks c<nbk scan row c in place (exclusive), total->rowsum
  if (c < nbk) {
    const int rbase = c * nblk;
    int vals[4];
    int run = 0;
#pragma unroll
    for (int k = 0; k < 4; ++k) {
      const int idx = t * 4 + k;
      const int v = (idx < nblk) ? cnt[rbase + idx] : 0;
      vals[k] = v;
      run += v;
    }
    red[t] = run;
    __syncthreads();
    for (int off = 1; off < 256; off <<= 1) {
      const int u = (t >= off) ? red[t - off] : 0;
      __syncthreads();
      red[t] += u;
      __syncthreads();
    }
    int acc = red[t] - run;  // exclusive prefix of this thread's span
    if (t == 0) rowsum[c] = red[255];
#pragma unroll
    for (int k = 0; k < 4; ++k) {
      const int idx = t * 4 + k;
      if (idx < nblk) {
        cnt[rbase + idx] = acc;
        acc += vals[k];
      }
    }
  }
  __threadfence();
  grid.sync();

  // ---- Phase B2: block 0 scans rowsum[nbk] -> rowbase (exclusive); total at
  // rowbase[nbk].
  if (c == 0) {
    const int v = (t < nbk) ? rowsum[t] : 0;
    red[t] = v;
    __syncthreads();
    for (int off = 1; off < 256; off <<= 1) {
      const int u = (t >= off) ? red[t - off] : 0;
      __syncthreads();
      red[t] += u;
      __syncthreads();
    }
    if (t < nbk) rowbase[t] = red[t] - v;
    if (t == 0) rowbase[nbk] = red[255];
  }
  __threadfence();
  grid.sync();

  // ---- Phase C: scatter this chunk's edges via LDS cursors ----
  if (t < nbk) cur[t] = rowbase[t] + cnt[t * nblk + c];
  __syncthreads();
  for (int e = base + t * 4; e < end; e += 1024) {
    if (e + 3 < end) {
      const int4 s4 = *(const int4*)(src + e);
      const int4 d4 = *(const int4*)(dst + e);
      int p0 = atomicAdd(&cur[d4.x >> BKT_SHIFT], 1);
      tmp[p0] = (s4.x << 9) | (d4.x & 511);
      int p1 = atomicAdd(&cur[d4.y >> BKT_SHIFT], 1);
      tmp[p1] = (s4.y << 9) | (d4.y & 511);
      int p2 = atomicAdd(&cur[d4.z >> BKT_SHIFT], 1);
      tmp[p2] = (s4.z << 9) | (d4.z & 511);
      int p3 = atomicAdd(&cur[d4.w >> BKT_SHIFT], 1);
      tmp[p3] = (s4.w << 9) | (d4.w & 511);
    } else {
      for (int k = e; k < end; ++k) {
        const int d = dst[k];
        const int pos = atomicAdd(&cur[d >> BKT_SHIFT], 1);
        tmp[pos] = (src[k] << 9) | (d & 511);
      }
    }
  }
}

// B: one block per bucket (1024 threads). LDS node histogram -> 512-wide LDS
// scan -> row_ptr (coalesced) -> LDS-cursor fill of pairs -> FUSED cast_scale
// for this bucket's 512 nodes (dinv held in LDS; dinv global array deleted).
__global__ __launch_bounds__(1024) void bucket_build(const int* __restrict__ tmp,
                                                     const int* __restrict__ rowbase,
                                                     int* __restrict__ row_ptr,
                                                     int* __restrict__ pairs,
                                                     const float* __restrict__ x,
                                                     __half* __restrict__ xs,
                                                     __half* __restrict__ hs,
                                                     int n, int nbk, int E) {
  __shared__ int hist[BKT_NODES];
  __shared__ int scn[BKT_NODES];
  const int b = blockIdx.x;
  const int t = threadIdx.x;
  const int node0 = b << BKT_SHIFT;
  if (t < BKT_NODES) hist[t] = 0;
  __syncthreads();
  const int s = rowbase[b];
  const int e = rowbase[b + 1];
  for (int k = s + t; k < e; k += 1024) atomicAdd(&hist[tmp[k] & 511], 1);
  __syncthreads();
  int v = 0;
  if (t < BKT_NODES) {
    v = hist[t];
    scn[t] = v;
  }
  __syncthreads();
  for (int off = 1; off < BKT_NODES; off <<= 1) {
    int u = 0;
    if (t < BKT_NODES && t >= off) u = scn[t - off];
    __syncthreads();
    if (t < BKT_NODES) scn[t] += u;
    __syncthreads();
  }
  if (t < BKT_NODES) {
    const int excl = s + scn[t] - v;  // exclusive prefix = CSR start of node0+t
    const int node = node0 + t;
    if (node < n) row_ptr[node] = excl;
    if (b == nbk - 1 && t == 0) row_ptr[n] = E;
    hist[t] = excl;                          // reuse as cursor
    scn[t] = __float_as_int(rsqrtf(1.0f + (float)v));  // stash dinv for cast
  }
  __syncthreads();
  for (int k = s + t; k < e; k += 1024) {
    const int w = tmp[k];
    const int pos = atomicAdd(&hist[w & 511], 1);
    pairs[pos] = w >> 9;
  }
  // ---- fused cast_scale: xs[node] = dinv[node] * x[node] (fp16) ----
  const int nloc = imin(BKT_NODES, n - node0);
  for (int idx = t; idx < nloc * 16; idx += 1024) {
    const int nl = idx >> 4, f4 = idx & 15;
    const float4 v4 = ((const float4*)x)[(size_t)(node0 + nl) * 16 + f4];
    const float d = __int_as_float(scn[nl]);
    __half2* o = (__half2*)(xs + (size_t)(node0 + nl) * 64 + f4 * 4);
    o[0] = __floats2half2_rn(d * v4.x, d * v4.y);
    o[1] = __floats2half2_rn(d * v4.z, d * v4.w);
  }
  // sentinel rows (xs[n], hs[n] = 0); hs aliases tmp but row n is at byte
  // offset n*128 (12.8MB) > E*4 (6.4MB), so no clash with live tmp data.
  if (b == 0 && t < 32) {
    if (t < 16)
      ((float2*)(xs + (size_t)n * 64))[t] = make_float2(0.f, 0.f);
    else
      ((float2*)(hs + (size_t)n * 64))[t - 16] = make_float2(0.f, 0.f);
  }
}

// ---------------- aggregation + fused dense via MFMA (R8/R11 config) -------
// Wave handles 16 rows (4 groups of 4 rows interleaved). Per row: 8 edge
// slots (lane=8g+q, 16B of 8 halves/lane), packed-half2 accumulate; 4 rows'
// pairs-prefetch + gather chains run concurrently. One xor-32 fold (slots
// 8->4), self-term on g==0, di-scale, store to wave-private LDS A-tile
// ylds[row][(g&3)*64 + 8q+c] (K'=256; last 4-slot reduction rides the MFMA
// K-dim, B = W replicated over the 4 slots). 8 k-steps x 4 n-tiles of
// mfma_f32_16x16x32_f16, bias in C-init.
// A layout: A[m=lane&15][k=(lane>>4)*8+j]; C/D: col=lane&15, row=quad*4+reg.

#define YSTRIDE 264  // 256 + 8 halves pad

__global__ __launch_bounds__(256, 4) void agg_layer1(const __half* __restrict__ xs,
                                                     const int* __restrict__ pairs,
                                                     const int* __restrict__ row_ptr,
                                                     const float* __restrict__ W1,
                                                     const float* __restrict__ b1,
                                                     __half* __restrict__ hs, int n) {
  __shared__ _Float16 ylds_all[4][16 * YSTRIDE];
  __shared__ float dilds_all[4][16];
  const int wv = threadIdx.x >> 6;
  _Float16* ylds = ylds_all[wv];
  float* dilds = dilds_all[wv];
  const int lane = threadIdx.x & 63;
  const int g = lane >> 3, q = lane & 7;
  const int quad = lane >> 4, col = lane & 15;

  // B-fragments: k = s2*32 + quad*8 + jj; feature = k & 63 -> sW = s2 & 1.
  half8 bfrag[2][4];
#pragma unroll
  for (int s = 0; s < 2; ++s)
#pragma unroll
    for (int t = 0; t < 4; ++t)
#pragma unroll
      for (int jj = 0; jj < 8; ++jj)
        bfrag[s][t][jj] = (_Float16)W1[(s * 32 + quad * 8 + jj) * 64 + t * 16 + col];
  float bias[4];
#pragma unroll
  for (int t = 0; t < 4; ++t) bias[t] = b1[t * 16 + col];

  const int ntiles = (n + 15) >> 4;
  for (int tile = blockIdx.x * 4 + wv; tile < ntiles; tile += gridDim.x * 4) {
    const int row0 = tile << 4;
#pragma unroll 1
    for (int rg = 0; rg < 4; ++rg) {  // 4 rows interleaved per group
      int start[4], end[4], idx[4];
      __half2 acc[4][4];
      int maxdeg = 0;
#pragma unroll
      for (int j = 0; j < 4; ++j) {
        const int i = row0 + rg * 4 + j;
        start[j] = 0; end[j] = 0;
        if (i < n) { start[j] = row_ptr[i]; end[j] = row_ptr[i + 1]; }
        maxdeg = imax(maxdeg, end[j] - start[j]);
#pragma unroll
        for (int k = 0; k < 4; ++k) acc[j][k] = u2h(0u);
        idx[j] = (start[j] + g < end[j]) ? pairs[start[j] + g] : n;
      }
      const int iters = (maxdeg + 7) >> 3;
#pragma unroll 1
      for (int it = 0; it < iters; ++it) {
        int nidx[4];
#pragma unroll
        for (int j = 0; j < 4; ++j) {
          const int ofs2 = start[j] + (it + 1) * 8 + g;
          nidx[j] = (ofs2 < end[j]) ? pairs[ofs2] : n;
        }
#pragma unroll
        for (int j = 0; j < 4; ++j) {
          const float4 rr = *(const float4*)(xs + (size_t)idx[j] * 64 + q * 8);
          const __half2* hp = (const __half2*)&rr;
#pragma unroll
          for (int k = 0; k < 4; ++k) acc[j][k] = __hadd2(acc[j][k], hp[k]);
        }
#pragma unroll
        for (int j = 0; j < 4; ++j) idx[j] = nidx[j];
      }
#pragma unroll
      for (int j = 0; j < 4; ++j) {
        const int i = row0 + rg * 4 + j;
        // self term (once, on g==0 lanes)
        if (g == 0 && i < n) {
          const float4 sr = *(const float4*)(xs + (size_t)i * 64 + q * 8);
          const __half2* hp = (const __half2*)&sr;
#pragma unroll
          for (int k = 0; k < 4; ++k) acc[j][k] = __hadd2(acc[j][k], hp[k]);
        }
        // fold slots g and g^4 (lane xor 32)
#pragma unroll
        for (int k = 0; k < 4; ++k) {
          unsigned u = __shfl_xor(h2u(acc[j][k]), 32);
          acc[j][k] = __hadd2(acc[j][k], u2h(u));
        }
        const float di = rsqrtf((float)(1 + end[j] - start[j]));
        const __half hdi = __float2half(di);
        const __half2 di2 = __halves2half2(hdi, hdi);
        uint4v st;
        st.x = h2u(__hmul2(di2, acc[j][0]));
        st.y = h2u(__hmul2(di2, acc[j][1]));
        st.z = h2u(__hmul2(di2, acc[j][2]));
        st.w = h2u(__hmul2(di2, acc[j][3]));
        *(uint4v*)(ylds + (rg * 4 + j) * YSTRIDE + (g & 3) * 64 + q * 8) = st;
        if (lane == 0) dilds[rg * 4 + j] = di;
      }
    }
    // MFMA: D = A(16x256) * B'(256x64) + bias
    float4v acc[4];
#pragma unroll
    for (int t = 0; t < 4; ++t) acc[t] = (float4v){bias[t], bias[t], bias[t], bias[t]};
#pragma unroll
    for (int s2 = 0; s2 < 8; ++s2) {
      half8 af = *(half8*)(ylds + col * YSTRIDE + s2 * 32 + quad * 8);
      const int sW = s2 & 1;
#pragma unroll
      for (int t = 0; t < 4; ++t)
        acc[t] = __builtin_amdgcn_mfma_f32_16x16x32_f16(af, bfrag[sW][t], acc[t], 0, 0, 0);
    }
    const float4 dis = *(const float4*)(dilds + quad * 4);
    const float dd[4] = {dis.x, dis.y, dis.z, dis.w};
#pragma unroll
    for (int t = 0; t < 4; ++t)
#pragma unroll
      for (int reg = 0; reg < 4; ++reg) {
        const int row = row0 + quad * 4 + reg;
        if (row < n)
          hs[(size_t)row * 64 + t * 16 + col] =
              __float2half(dd[reg] * fmaxf(acc[t][reg], 0.f));
      }
  }
}

// Layer 2: same structure; B' = [Wmu | Wlv] (64 cols), fp32 outputs.
__global__ __launch_bounds__(256, 4) void agg_layer2(const __half* __restrict__ hsin,
                                                     const int* __restrict__ pairs,
                                                     const int* __restrict__ row_ptr,
                                                     const float* __restrict__ Wmu,
                                                     const float* __restrict__ bmu,
                                                     const float* __restrict__ Wlv,
                                                     const float* __restrict__ blv,
                                                     float* __restrict__ out_mu,
                                                     float* __restrict__ out_lv, int n) {
  __shared__ _Float16 ylds_all[4][16 * YSTRIDE];
  const int wv = threadIdx.x >> 6;
  _Float16* ylds = ylds_all[wv];
  const int lane = threadIdx.x & 63;
  const int g = lane >> 3, q = lane & 7;
  const int quad = lane >> 4, col = lane & 15;

  half8 bfrag[2][4];
#pragma unroll
  for (int s = 0; s < 2; ++s)
#pragma unroll
    for (int t = 0; t < 4; ++t) {
      const int j = t * 16 + col;
      const float* W = (j < 32) ? Wmu : Wlv;
      const int jc = j & 31;
#pragma unroll
      for (int jj = 0; jj < 8; ++jj)
        bfrag[s][t][jj] = (_Float16)W[(s * 32 + quad * 8 + jj) * 32 + jc];
    }
  float bias[4];
#pragma unroll
  for (int t = 0; t < 4; ++t) {
    const int j = t * 16 + col;
    bias[t] = (j < 32) ? bmu[j] : blv[j - 32];
  }

  const int ntiles = (n + 15) >> 4;
  for (int tile = blockIdx.x * 4 + wv; tile < ntiles; tile += gridDim.x * 4) {
    const int row0 = tile << 4;
#pragma unroll 1
    for (int rg = 0; rg < 4; ++rg) {
      int start[4], end[4], idx[4];
      __half2 acc[4][4];
      int maxdeg = 0;
#pragma unroll
      for (int j = 0; j < 4; ++j) {
        const int i = row0 + rg * 4 + j;
        start[j] = 0; end[j] = 0;
        if (i < n) { start[j] = row_ptr[i]; end[j] = row_ptr[i + 1]; }
        maxdeg = imax(maxdeg, end[j] - start[j]);
#pragma unroll
        for (int k = 0; k < 4; ++k) acc[j][k] = u2h(0u);
        idx[j] = (start[j] + g < end[j]) ? pairs[start[j] + g] : n;
      }
      const int iters = (maxdeg + 7) >> 3;
#pragma unroll 1
      for (int it = 0; it < iters; ++it) {
        int nidx[4];
#pragma unroll
        for (int j = 0; j < 4; ++j) {
          const int ofs2 = start[j] + (it + 1) * 8 + g;
          nidx[j] = (ofs2 < end[j]) ? pairs[ofs2] : n;
        }
#pragma unroll
        for (int j = 0; j < 4; ++j) {
          const float4 rr = *(const float4*)(hsin + (size_t)idx[j] * 64 + q * 8);
          const __half2* hp = (const __half2*)&rr;
#pragma unroll
          for (int k = 0; k < 4; ++k) acc[j][k] = __hadd2(acc[j][k], hp[k]);
        }
#pragma unroll
        for (int j = 0; j < 4; ++j) idx[j] = nidx[j];
      }
#pragma unroll
      for (int j = 0; j < 4; ++j) {
        const int i = row0 + rg * 4 + j;
        if (g == 0 && i < n) {
          const float4 sr = *(const float4*)(hsin + (size_t)i * 64 + q * 8);
          const __half2* hp = (const __half2*)&sr;
#pragma unroll
          for (int k = 0; k < 4; ++k) acc[j][k] = __hadd2(acc[j][k], hp[k]);
        }
#pragma unroll
        for (int k = 0; k < 4; ++k) {
          unsigned u = __shfl_xor(h2u(acc[j][k]), 32);
          acc[j][k] = __hadd2(acc[j][k], u2h(u));
        }
        const float di = rsqrtf((float)(1 + end[j] - start[j]));
        const __half hdi = __float2half(di);
        const __half2 di2 = __halves2half2(hdi, hdi);
        uint4v st;
        st.x = h2u(__hmul2(di2, acc[j][0]));
        st.y = h2u(__hmul2(di2, acc[j][1]));
        st.z = h2u(__hmul2(di2, acc[j][2]));
        st.w = h2u(__hmul2(di2, acc[j][3]));
        *(uint4v*)(ylds + (rg * 4 + j) * YSTRIDE + (g & 3) * 64 + q * 8) = st;
      }
    }
    float4v acc[4];
#pragma unroll
    for (int t = 0; t < 4; ++t) acc[t] = (float4v){bias[t], bias[t], bias[t], bias[t]};
#pragma unroll
    for (int s2 = 0; s2 < 8; ++s2) {
      half8 af = *(half8*)(ylds + col * YSTRIDE + s2 * 32 + quad * 8);
      const int sW = s2 & 1;
#pragma unroll
      for (int t = 0; t < 4; ++t)
        acc[t] = __builtin_amdgcn_mfma_f32_16x16x32_f16(af, bfrag[sW][t], acc[t], 0, 0, 0);
    }
#pragma unroll
    for (int t = 0; t < 4; ++t)
#pragma unroll
      for (int reg = 0; reg < 4; ++reg) {
        const int row = row0 + quad * 4 + reg;
        if (row < n) {
          const int j = t * 16 + col;
          if (j < 32)
            out_mu[(size_t)row * 32 + j] = acc[t][reg];
          else
            out_lv[(size_t)row * 32 + (j - 32)] = acc[t][reg];
        }
      }
  }
}

extern "C" void kernel_launch(void* const* d_in, const int* in_sizes, int n_in,
                              void* d_out, int out_size, void* d_ws, size_t ws_size,
                              hipStream_t stream) {
  const float* x = (const float*)d_in[0];
  const int* ei = (const int*)d_in[1];  // [2, E] row-major int32
  const float* W1 = (const float*)d_in[2];
  const float* b1 = (const float*)d_in[3];
  const float* Wmu = (const float*)d_in[4];
  const float* bmu = (const float*)d_in[5];
  const float* Wlv = (const float*)d_in[6];
  const float* blv = (const float*)d_in[7];

  const int N = in_sizes[0] / 64;
  const int E = in_sizes[1] / 2;
  const int* src = ei;
  const int* dst = ei + E;

  const int NBK = (N + BKT_NODES - 1) >> BKT_SHIFT;  // 196 buckets (<=256)
  const int NBLK = (E + CHUNK - 1) / CHUNK;          // 782 chunks (<=1024)
  const int FL = NBK * NBLK;                         // ~153k

  auto align256 = [](size_t v) { return (v + 255) & ~(size_t)255; };
  char* p = (char*)d_ws;
  int* row_ptr = (int*)p;  p += align256((size_t)(N + 1) * 4);
  int* rowsum = (int*)p;   p += align256((size_t)256 * 4);
  int* rowbase = (int*)p;  p += align256((size_t)257 * 4);
  int* cnt = (int*)p;      p += align256((size_t)FL * 4);
  int* pairs = (int*)p;    p += align256((size_t)E * 4);
  __half* xs = (__half*)p; p += align256((size_t)(N + 1) * 64 * 2);
  size_t tmp_bytes = (size_t)E * 4;  // packed int
  size_t hs_bytes = (size_t)(N + 1) * 64 * 2;
  int* tmp = (int*)p;      // union: tmp dead after bucket_build; hs written later
  __half* hs = (__half*)p;
  p += align256(tmp_bytes > hs_bytes ? tmp_bytes : hs_bytes);

  float* out_mu = (float*)d_out;
  float* out_lv = out_mu + (size_t)N * 32;

  // --- CSR build: ONE cooperative kernel (count+scan+scatter), then
  //     per-bucket build with fused cast_scale ---
  {
    void* args[] = {(void*)&src, (void*)&dst, (void*)&cnt, (void*)&rowsum,
                    (void*)&rowbase, (void*)&tmp, (void*)&E, (void*)&NBK,
                    (void*)&NBLK};
    hipLaunchCooperativeKernel(reinterpret_cast<void*>(coop_build), dim3(NBLK),
                               dim3(256), args, 0, stream);
  }
  bucket_build<<<NBK, 1024, 0, stream>>>(tmp, rowbase, row_ptr, pairs, x, xs, hs,
                                         N, NBK, E);

  // --- aggregation + fused dense layers (MFMA epilogue) ---
  const int ntiles = (N + 15) / 16;
  const int ablocks = (ntiles + 3) / 4;  // 1 tile (16 rows) per wave
  agg_layer1<<<ablocks, 256, 0, stream>>>(xs, pairs, row_ptr, W1, b1, hs, N);
  agg_layer2<<<ablocks, 256, 0, stream>>>(hs, pairs, row_ptr, Wmu, bmu, Wlv, blv,
                                          out_mu, out_lv, N);
}

// Round 5
// 236.624 us; speedup vs baseline: 2.7385x; 2.7385x over previous
//
#include <hip/hip_runtime.h>
#include <hip/hip_fp16.h>

// GCN VGAE encoder:
//   h  = relu((A @ x) @ W1 + b1)          [associativity: A(xW) == (Ax)W]
//   mu = (A @ h) @ Wmu + bmu ; lv = (A @ h) @ Wlv + blv
// A = D^-1/2 (Adj + I) D^-1/2, deg on dst side. dinv folded into tables:
//   xs[s]=dinv_s*x[s]; hs[i]=dinv_i*relu(...); y_i = dinv_i*(sum_e xs[src]+xs[i])
//
// R16: minimum-dispatch build with ONLY plain launches. Measured primitive
// costs: same-addr global fetch-atomic ~235ns (R14, dead), grid.sync ~130us
// (R15, dead), kernel-boundary gap ~10-13us (R13/R14 dispatch accounting).
// So: cut boundaries, keep R13's proven phase bodies.
//  * scan_rows (196 blocks): per-bucket row scan of cnt[b][0..782) in-place
//    + rowsum[b]. Replaces block_sums/scan_bsums/scan_apply (3 kernels).
//  * bucket_scatter/bucket_build: recompute the 196-wide cross-bucket base
//    locally (196 ints from L2 + 8-step LDS scan, <1us) -- no extra kernel.
//  * cast_scale fused into bucket_build (dinv already in LDS there).
// Pipeline: count -> scan_rows -> scatter -> build(+cast) -> agg1 -> agg2
// (6 dispatches; R13 had 9). Aggs: exact R11 config (proven 56.6us; gather
// plateau confirmed by 6 failed configs).

#define BKT_SHIFT 9
#define BKT_NODES 512
#define CHUNK 2048

typedef __attribute__((ext_vector_type(8))) _Float16 half8;
typedef __attribute__((ext_vector_type(4))) float float4v;
typedef __attribute__((ext_vector_type(4))) unsigned uint4v;

__device__ __forceinline__ int imin(int a, int b) { return a < b ? a : b; }
__device__ __forceinline__ int imax(int a, int b) { return a > b ? a : b; }
__device__ __forceinline__ unsigned h2u(__half2 v) {
  union { __half2 h; unsigned u; } c; c.h = v; return c.u;
}
__device__ __forceinline__ __half2 u2h(unsigned x) {
  union { unsigned u; __half2 h; } c; c.u = x; return c.h;
}

// ---------------- A0: per-chunk bucket histogram ---------------------------
// cnt[bucket*nblk + chunk] (bucket-major). Dual sub-histograms, int4 loads.
__global__ __launch_bounds__(256) void bucket_count(const int* __restrict__ dst,
                                                    int* __restrict__ cnt,
                                                    int E, int nbk, int nblk) {
  __shared__ int hist[2][256];
  const int t = threadIdx.x;
  const int h = (t >> 7) & 1;  // waves 0-1 -> copy 0, waves 2-3 -> copy 1
  hist[0][t] = 0;
  hist[1][t] = 0;
  __syncthreads();
  const int base = blockIdx.x * CHUNK;
  const int end = imin(base + CHUNK, E);
  for (int e = base + t * 4; e < end; e += 1024) {
    if (e + 3 < end) {
      const int4 d4 = *(const int4*)(dst + e);
      atomicAdd(&hist[h][d4.x >> BKT_SHIFT], 1);
      atomicAdd(&hist[h][d4.y >> BKT_SHIFT], 1);
      atomicAdd(&hist[h][d4.z >> BKT_SHIFT], 1);
      atomicAdd(&hist[h][d4.w >> BKT_SHIFT], 1);
    } else {
      for (int k = e; k < end; ++k) atomicAdd(&hist[h][dst[k] >> BKT_SHIFT], 1);
    }
  }
  __syncthreads();
  if (t < nbk) cnt[t * nblk + blockIdx.x] = hist[0][t] + hist[1][t];
}

// ---------------- A1: per-bucket row scan (in place) -----------------------
// Block b scans cnt[b][0..nblk) -> within-row exclusive prefix; rowsum[b] =
// row total. Requires nblk <= 1024 (4 elems/thread).
__global__ __launch_bounds__(256) void scan_rows(int* __restrict__ cnt,
                                                 int* __restrict__ rowsum,
                                                 int nbk, int nblk) {
  __shared__ int red[256];
  const int b = blockIdx.x;
  const int t = threadIdx.x;
  const int rbase = b * nblk;
  int vals[4];
  int run = 0;
#pragma unroll
  for (int k = 0; k < 4; ++k) {
    const int idx = t * 4 + k;
    const int v = (idx < nblk) ? cnt[rbase + idx] : 0;
    vals[k] = v;
    run += v;
  }
  red[t] = run;
  __syncthreads();
  for (int off = 1; off < 256; off <<= 1) {
    const int u = (t >= off) ? red[t - off] : 0;
    __syncthreads();
    red[t] += u;
    __syncthreads();
  }
  int acc = red[t] - run;  // exclusive prefix of this thread's span
  if (t == 255) rowsum[b] = red[255];
#pragma unroll
  for (int k = 0; k < 4; ++k) {
    const int idx = t * 4 + k;
    if (idx < nblk) {
      cnt[rbase + idx] = acc;
      acc += vals[k];
    }
  }
}

// ---------------- A2: scatter with LDS cursors -----------------------------
// Prologue recomputes cross-bucket bases locally (scan of rowsum[0..nbk)).
// tmp entry packed: (src << 9) | (dst & 511)  [src < 2^17 for N=100k].
__global__ __launch_bounds__(256) void bucket_scatter(const int* __restrict__ src,
                                                      const int* __restrict__ dst,
                                                      const int* __restrict__ cnt,
                                                      const int* __restrict__ rowsum,
                                                      int* __restrict__ tmp,
                                                      int E, int nbk, int nblk) {
  __shared__ int cur[256];
  __shared__ int red[256];
  const int t = threadIdx.x;
  const int c = blockIdx.x;
  const int v = (t < nbk) ? rowsum[t] : 0;
  red[t] = v;
  __syncthreads();
  for (int off = 1; off < 256; off <<= 1) {
    const int u = (t >= off) ? red[t - off] : 0;
    __syncthreads();
    red[t] += u;
    __syncthreads();
  }
  if (t < nbk) cur[t] = (red[t] - v) + cnt[t * nblk + c];
  __syncthreads();
  const int base = c * CHUNK;
  const int end = imin(base + CHUNK, E);
  for (int e = base + t * 4; e < end; e += 1024) {
    if (e + 3 < end) {
      const int4 s4 = *(const int4*)(src + e);
      const int4 d4 = *(const int4*)(dst + e);
      int p0 = atomicAdd(&cur[d4.x >> BKT_SHIFT], 1);
      tmp[p0] = (s4.x << 9) | (d4.x & 511);
      int p1 = atomicAdd(&cur[d4.y >> BKT_SHIFT], 1);
      tmp[p1] = (s4.y << 9) | (d4.y & 511);
      int p2 = atomicAdd(&cur[d4.z >> BKT_SHIFT], 1);
      tmp[p2] = (s4.z << 9) | (d4.z & 511);
      int p3 = atomicAdd(&cur[d4.w >> BKT_SHIFT], 1);
      tmp[p3] = (s4.w << 9) | (d4.w & 511);
    } else {
      for (int k = e; k < end; ++k) {
        const int d = dst[k];
        const int pos = atomicAdd(&cur[d >> BKT_SHIFT], 1);
        tmp[pos] = (src[k] << 9) | (d & 511);
      }
    }
  }
}

// ---------------- B: per-bucket CSR build + fused cast_scale ---------------
// 1024 threads/block, 196 blocks. Local rowbase scan -> LDS node histogram ->
// 512-wide LDS scan -> row_ptr (coalesced) -> LDS-cursor pairs fill -> fused
// xs cast for this bucket's 512 nodes (dinv stashed in LDS).
__global__ __launch_bounds__(1024) void bucket_build(const int* __restrict__ tmp,
                                                     const int* __restrict__ rowsum,
                                                     int* __restrict__ row_ptr,
                                                     int* __restrict__ pairs,
                                                     const float* __restrict__ x,
                                                     __half* __restrict__ xs,
                                                     __half* __restrict__ hs,
                                                     int n, int nbk, int E) {
  __shared__ int hist[BKT_NODES];
  __shared__ int scn[BKT_NODES];
  __shared__ int red[256];
  __shared__ int s_sh, e_sh;
  const int b = blockIdx.x;
  const int t = threadIdx.x;
  const int node0 = b << BKT_SHIFT;
  // local rowbase: scan rowsum[0..nbk) with the first 256 threads
  int v0 = 0;
  if (t < 256) {
    v0 = (t < nbk) ? rowsum[t] : 0;
    red[t] = v0;
  }
  if (t < BKT_NODES) hist[t] = 0;
  __syncthreads();
  for (int off = 1; off < 256; off <<= 1) {
    int u = 0;
    if (t < 256 && t >= off) u = red[t - off];
    __syncthreads();
    if (t < 256) red[t] += u;
    __syncthreads();
  }
  if (t == 0) {
    const int incl = red[b];       // inclusive sum through bucket b
    e_sh = incl;
    s_sh = incl - rowsum[b];
  }
  __syncthreads();
  const int s = s_sh;
  const int e = e_sh;
  for (int k = s + t; k < e; k += 1024) atomicAdd(&hist[tmp[k] & 511], 1);
  __syncthreads();
  int v = 0;
  if (t < BKT_NODES) {
    v = hist[t];
    scn[t] = v;
  }
  __syncthreads();
  for (int off = 1; off < BKT_NODES; off <<= 1) {
    int u = 0;
    if (t < BKT_NODES && t >= off) u = scn[t - off];
    __syncthreads();
    if (t < BKT_NODES) scn[t] += u;
    __syncthreads();
  }
  if (t < BKT_NODES) {
    const int excl = s + scn[t] - v;  // exclusive prefix = CSR start of node0+t
    const int node = node0 + t;
    if (node < n) row_ptr[node] = excl;
    if (b == nbk - 1 && t == 0) row_ptr[n] = E;
    hist[t] = excl;                                    // reuse as cursor
    scn[t] = __float_as_int(rsqrtf(1.0f + (float)v));  // stash dinv for cast
  }
  __syncthreads();
  for (int k = s + t; k < e; k += 1024) {
    const int w = tmp[k];
    const int pos = atomicAdd(&hist[w & 511], 1);
    pairs[pos] = w >> 9;
  }
  // ---- fused cast_scale: xs[node] = dinv[node] * x[node] (fp16) ----
  const int nloc = imin(BKT_NODES, n - node0);
  for (int idx = t; idx < nloc * 16; idx += 1024) {
    const int nl = idx >> 4, f4 = idx & 15;
    const float4 v4 = ((const float4*)x)[(size_t)(node0 + nl) * 16 + f4];
    const float d = __int_as_float(scn[nl]);
    __half2* o = (__half2*)(xs + (size_t)(node0 + nl) * 64 + f4 * 4);
    o[0] = __floats2half2_rn(d * v4.x, d * v4.y);
    o[1] = __floats2half2_rn(d * v4.z, d * v4.w);
  }
  // sentinel rows (xs[n], hs[n] = 0); hs aliases tmp but row n sits at byte
  // offset n*128 (12.8MB) > E*4 (6.4MB), so no clash with live tmp data.
  if (b == 0 && t < 32) {
    if (t < 16)
      ((float2*)(xs + (size_t)n * 64))[t] = make_float2(0.f, 0.f);
    else
      ((float2*)(hs + (size_t)n * 64))[t - 16] = make_float2(0.f, 0.f);
  }
}

// ---------------- aggregation + fused dense via MFMA (R8/R11 config) -------
// Wave handles 16 rows (4 groups of 4 rows interleaved). Per row: 8 edge
// slots (lane=8g+q, 16B of 8 halves/lane), packed-half2 accumulate; 4 rows'
// pairs-prefetch + gather chains run concurrently. One xor-32 fold (slots
// 8->4), self-term on g==0, di-scale, store to wave-private LDS A-tile
// ylds[row][(g&3)*64 + 8q+c] (K'=256; last 4-slot reduction rides the MFMA
// K-dim, B = W replicated over the 4 slots). 8 k-steps x 4 n-tiles of
// mfma_f32_16x16x32_f16, bias in C-init.
// A layout: A[m=lane&15][k=(lane>>4)*8+j]; C/D: col=lane&15, row=quad*4+reg.

#define YSTRIDE 264  // 256 + 8 halves pad

__global__ __launch_bounds__(256, 4) void agg_layer1(const __half* __restrict__ xs,
                                                     const int* __restrict__ pairs,
                                                     const int* __restrict__ row_ptr,
                                                     const float* __restrict__ W1,
                                                     const float* __restrict__ b1,
                                                     __half* __restrict__ hs, int n) {
  __shared__ _Float16 ylds_all[4][16 * YSTRIDE];
  __shared__ float dilds_all[4][16];
  const int wv = threadIdx.x >> 6;
  _Float16* ylds = ylds_all[wv];
  float* dilds = dilds_all[wv];
  const int lane = threadIdx.x & 63;
  const int g = lane >> 3, q = lane & 7;
  const int quad = lane >> 4, col = lane & 15;

  // B-fragments: k = s2*32 + quad*8 + jj; feature = k & 63 -> sW = s2 & 1.
  half8 bfrag[2][4];
#pragma unroll
  for (int s = 0; s < 2; ++s)
#pragma unroll
    for (int t = 0; t < 4; ++t)
#pragma unroll
      for (int jj = 0; jj < 8; ++jj)
        bfrag[s][t][jj] = (_Float16)W1[(s * 32 + quad * 8 + jj) * 64 + t * 16 + col];
  float bias[4];
#pragma unroll
  for (int t = 0; t < 4; ++t) bias[t] = b1[t * 16 + col];

  const int ntiles = (n + 15) >> 4;
  for (int tile = blockIdx.x * 4 + wv; tile < ntiles; tile += gridDim.x * 4) {
    const int row0 = tile << 4;
#pragma unroll 1
    for (int rg = 0; rg < 4; ++rg) {  // 4 rows interleaved per group
      int start[4], end[4], idx[4];
      __half2 acc[4][4];
      int maxdeg = 0;
#pragma unroll
      for (int j = 0; j < 4; ++j) {
        const int i = row0 + rg * 4 + j;
        start[j] = 0; end[j] = 0;
        if (i < n) { start[j] = row_ptr[i]; end[j] = row_ptr[i + 1]; }
        maxdeg = imax(maxdeg, end[j] - start[j]);
#pragma unroll
        for (int k = 0; k < 4; ++k) acc[j][k] = u2h(0u);
        idx[j] = (start[j] + g < end[j]) ? pairs[start[j] + g] : n;
      }
      const int iters = (maxdeg + 7) >> 3;
#pragma unroll 1
      for (int it = 0; it < iters; ++it) {
        int nidx[4];
#pragma unroll
        for (int j = 0; j < 4; ++j) {
          const int ofs2 = start[j] + (it + 1) * 8 + g;
          nidx[j] = (ofs2 < end[j]) ? pairs[ofs2] : n;
        }
#pragma unroll
        for (int j = 0; j < 4; ++j) {
          const float4 rr = *(const float4*)(xs + (size_t)idx[j] * 64 + q * 8);
          const __half2* hp = (const __half2*)&rr;
#pragma unroll
          for (int k = 0; k < 4; ++k) acc[j][k] = __hadd2(acc[j][k], hp[k]);
        }
#pragma unroll
        for (int j = 0; j < 4; ++j) idx[j] = nidx[j];
      }
#pragma unroll
      for (int j = 0; j < 4; ++j) {
        const int i = row0 + rg * 4 + j;
        // self term (once, on g==0 lanes)
        if (g == 0 && i < n) {
          const float4 sr = *(const float4*)(xs + (size_t)i * 64 + q * 8);
          const __half2* hp = (const __half2*)&sr;
#pragma unroll
          for (int k = 0; k < 4; ++k) acc[j][k] = __hadd2(acc[j][k], hp[k]);
        }
        // fold slots g and g^4 (lane xor 32)
#pragma unroll
        for (int k = 0; k < 4; ++k) {
          unsigned u = __shfl_xor(h2u(acc[j][k]), 32);
          acc[j][k] = __hadd2(acc[j][k], u2h(u));
        }
        const float di = rsqrtf((float)(1 + end[j] - start[j]));
        const __half hdi = __float2half(di);
        const __half2 di2 = __halves2half2(hdi, hdi);
        uint4v st;
        st.x = h2u(__hmul2(di2, acc[j][0]));
        st.y = h2u(__hmul2(di2, acc[j][1]));
        st.z = h2u(__hmul2(di2, acc[j][2]));
        st.w = h2u(__hmul2(di2, acc[j][3]));
        *(uint4v*)(ylds + (rg * 4 + j) * YSTRIDE + (g & 3) * 64 + q * 8) = st;
        if (lane == 0) dilds[rg * 4 + j] = di;
      }
    }
    // MFMA: D = A(16x256) * B'(256x64) + bias
    float4v acc[4];
#pragma unroll
    for (int t = 0; t < 4; ++t) acc[t] = (float4v){bias[t], bias[t], bias[t], bias[t]};
#pragma unroll
    for (int s2 = 0; s2 < 8; ++s2) {
      half8 af = *(half8*)(ylds + col * YSTRIDE + s2 * 32 + quad * 8);
      const int sW = s2 & 1;
#pragma unroll
      for (int t = 0; t < 4; ++t)
        acc[t] = __builtin_amdgcn_mfma_f32_16x16x32_f16(af, bfrag[sW][t], acc[t], 0, 0, 0);
    }
    const float4 dis = *(const float4*)(dilds + quad * 4);
    const float dd[4] = {dis.x, dis.y, dis.z, dis.w};
#pragma unroll
    for (int t = 0; t < 4; ++t)
#pragma unroll
      for (int reg = 0; reg < 4; ++reg) {
        const int row = row0 + quad * 4 + reg;
        if (row < n)
          hs[(size_t)row * 64 + t * 16 + col] =
              __float2half(dd[reg] * fmaxf(acc[t][reg], 0.f));
      }
  }
}

// Layer 2: same structure; B' = [Wmu | Wlv] (64 cols), fp32 outputs.
__global__ __launch_bounds__(256, 4) void agg_layer2(const __half* __restrict__ hsin,
                                                     const int* __restrict__ pairs,
                                                     const int* __restrict__ row_ptr,
                                                     const float* __restrict__ Wmu,
                                                     const float* __restrict__ bmu,
                                                     const float* __restrict__ Wlv,
                                                     const float* __restrict__ blv,
                                                     float* __restrict__ out_mu,
                                                     float* __restrict__ out_lv, int n) {
  __shared__ _Float16 ylds_all[4][16 * YSTRIDE];
  const int wv = threadIdx.x >> 6;
  _Float16* ylds = ylds_all[wv];
  const int lane = threadIdx.x & 63;
  const int g = lane >> 3, q = lane & 7;
  const int quad = lane >> 4, col = lane & 15;

  half8 bfrag[2][4];
#pragma unroll
  for (int s = 0; s < 2; ++s)
#pragma unroll
    for (int t = 0; t < 4; ++t) {
      const int j = t * 16 + col;
      const float* W = (j < 32) ? Wmu : Wlv;
      const int jc = j & 31;
#pragma unroll
      for (int jj = 0; jj < 8; ++jj)
        bfrag[s][t][jj] = (_Float16)W[(s * 32 + quad * 8 + jj) * 32 + jc];
    }
  float bias[4];
#pragma unroll
  for (int t = 0; t < 4; ++t) {
    const int j = t * 16 + col;
    bias[t] = (j < 32) ? bmu[j] : blv[j - 32];
  }

  const int ntiles = (n + 15) >> 4;
  for (int tile = blockIdx.x * 4 + wv; tile < ntiles; tile += gridDim.x * 4) {
    const int row0 = tile << 4;
#pragma unroll 1
    for (int rg = 0; rg < 4; ++rg) {
      int start[4], end[4], idx[4];
      __half2 acc[4][4];
      int maxdeg = 0;
#pragma unroll
      for (int j = 0; j < 4; ++j) {
        const int i = row0 + rg * 4 + j;
        start[j] = 0; end[j] = 0;
        if (i < n) { start[j] = row_ptr[i]; end[j] = row_ptr[i + 1]; }
        maxdeg = imax(maxdeg, end[j] - start[j]);
#pragma unroll
        for (int k = 0; k < 4; ++k) acc[j][k] = u2h(0u);
        idx[j] = (start[j] + g < end[j]) ? pairs[start[j] + g] : n;
      }
      const int iters = (maxdeg + 7) >> 3;
#pragma unroll 1
      for (int it = 0; it < iters; ++it) {
        int nidx[4];
#pragma unroll
        for (int j = 0; j < 4; ++j) {
          const int ofs2 = start[j] + (it + 1) * 8 + g;
          nidx[j] = (ofs2 < end[j]) ? pairs[ofs2] : n;
        }
#pragma unroll
        for (int j = 0; j < 4; ++j) {
          const float4 rr = *(const float4*)(hsin + (size_t)idx[j] * 64 + q * 8);
          const __half2* hp = (const __half2*)&rr;
#pragma unroll
          for (int k = 0; k < 4; ++k) acc[j][k] = __hadd2(acc[j][k], hp[k]);
        }
#pragma unroll
        for (int j = 0; j < 4; ++j) idx[j] = nidx[j];
      }
#pragma unroll
      for (int j = 0; j < 4; ++j) {
        const int i = row0 + rg * 4 + j;
        if (g == 0 && i < n) {
          const float4 sr = *(const float4*)(hsin + (size_t)i * 64 + q * 8);
          const __half2* hp = (const __half2*)&sr;
#pragma unroll
          for (int k = 0; k < 4; ++k) acc[j][k] = __hadd2(acc[j][k], hp[k]);
        }
#pragma unroll
        for (int k = 0; k < 4; ++k) {
          unsigned u = __shfl_xor(h2u(acc[j][k]), 32);
          acc[j][k] = __hadd2(acc[j][k], u2h(u));
        }
        const float di = rsqrtf((float)(1 + end[j] - start[j]));
        const __half hdi = __float2half(di);
        const __half2 di2 = __halves2half2(hdi, hdi);
        uint4v st;
        st.x = h2u(__hmul2(di2, acc[j][0]));
        st.y = h2u(__hmul2(di2, acc[j][1]));
        st.z = h2u(__hmul2(di2, acc[j][2]));
        st.w = h2u(__hmul2(di2, acc[j][3]));
        *(uint4v*)(ylds + (rg * 4 + j) * YSTRIDE + (g & 3) * 64 + q * 8) = st;
      }
    }
    float4v acc[4];
#pragma unroll
    for (int t = 0; t < 4; ++t) acc[t] = (float4v){bias[t], bias[t], bias[t], bias[t]};
#pragma unroll
    for (int s2 = 0; s2 < 8; ++s2) {
      half8 af = *(half8*)(ylds + col * YSTRIDE + s2 * 32 + quad * 8);
      const int sW = s2 & 1;
#pragma unroll
      for (int t = 0; t < 4; ++t)
        acc[t] = __builtin_amdgcn_mfma_f32_16x16x32_f16(af, bfrag[sW][t], acc[t], 0, 0, 0);
    }
#pragma unroll
    for (int t = 0; t < 4; ++t)
#pragma unroll
      for (int reg = 0; reg < 4; ++reg) {
        const int row = row0 + quad * 4 + reg;
        if (row < n) {
          const int j = t * 16 + col;
          if (j < 32)
            out_mu[(size_t)row * 32 + j] = acc[t][reg];
          else
            out_lv[(size_t)row * 32 + (j - 32)] = acc[t][reg];
        }
      }
  }
}

extern "C" void kernel_launch(void* const* d_in, const int* in_sizes, int n_in,
                              void* d_out, int out_size, void* d_ws, size_t ws_size,
                              hipStream_t stream) {
  const float* x = (const float*)d_in[0];
  const int* ei = (const int*)d_in[1];  // [2, E] row-major int32
  const float* W1 = (const float*)d_in[2];
  const float* b1 = (const float*)d_in[3];
  const float* Wmu = (const float*)d_in[4];
  const float* bmu = (const float*)d_in[5];
  const float* Wlv = (const float*)d_in[6];
  const float* blv = (const float*)d_in[7];

  const int N = in_sizes[0] / 64;
  const int E = in_sizes[1] / 2;
  const int* src = ei;
  const int* dst = ei + E;

  const int NBK = (N + BKT_NODES - 1) >> BKT_SHIFT;  // 196 buckets (<=256)
  const int NBLK = (E + CHUNK - 1) / CHUNK;          // 782 chunks (<=1024)
  const int FL = NBK * NBLK;                         // ~153k

  auto align256 = [](size_t v) { return (v + 255) & ~(size_t)255; };
  char* p = (char*)d_ws;
  int* row_ptr = (int*)p;  p += align256((size_t)(N + 1) * 4);
  int* rowsum = (int*)p;   p += align256((size_t)256 * 4);
  int* cnt = (int*)p;      p += align256((size_t)FL * 4);
  int* pairs = (int*)p;    p += align256((size_t)E * 4);
  __half* xs = (__half*)p; p += align256((size_t)(N + 1) * 64 * 2);
  size_t tmp_bytes = (size_t)E * 4;  // packed int
  size_t hs_bytes = (size_t)(N + 1) * 64 * 2;
  int* tmp = (int*)p;      // union: tmp dead after bucket_build; hs written later
  __half* hs = (__half*)p;
  p += align256(tmp_bytes > hs_bytes ? tmp_bytes : hs_bytes);

  float* out_mu = (float*)d_out;
  float* out_lv = out_mu + (size_t)N * 32;

  // --- CSR build: 4 plain dispatches, LDS atomics only ---
  bucket_count<<<NBLK, 256, 0, stream>>>(dst, cnt, E, NBK, NBLK);
  scan_rows<<<NBK, 256, 0, stream>>>(cnt, rowsum, NBK, NBLK);
  bucket_scatter<<<NBLK, 256, 0, stream>>>(src, dst, cnt, rowsum, tmp, E, NBK, NBLK);
  bucket_build<<<NBK, 1024, 0, stream>>>(tmp, rowsum, row_ptr, pairs, x, xs, hs,
                                         N, NBK, E);

  // --- aggregation + fused dense layers (MFMA epilogue) ---
  const int ntiles = (N + 15) / 16;
  const int ablocks = (ntiles + 3) / 4;  // 1 tile (16 rows) per wave
  agg_layer1<<<ablocks, 256, 0, stream>>>(xs, pairs, row_ptr, W1, b1, hs, N);
  agg_layer2<<<ablocks, 256, 0, stream>>>(hs, pairs, row_ptr, Wmu, bmu, Wlv, blv,
                                          out_mu, out_lv, N);
}

// Round 6
// 229.551 us; speedup vs baseline: 2.8229x; 1.0308x over previous
//
#include <hip/hip_runtime.h>
#include <hip/hip_fp16.h>

// GCN VGAE encoder:
//   h  = relu((A @ x) @ W1 + b1)          [associativity: A(xW) == (Ax)W]
//   mu = (A @ h) @ Wmu + bmu ; lv = (A @ h) @ Wlv + blv
// A = D^-1/2 (Adj + I) D^-1/2, deg on dst side. dinv folded into tables:
//   xs[s]=dinv_s*x[s]; hs[i]=dinv_i*relu(...); y_i = dinv_i*(sum_e xs[src]+xs[i])
//
// R17: line-granular build. Evidence: R14's WRITE_SIZE=77MB for 6.4MB of
// logical scatter writes (12x sub-line amplification); R13's size-packing and
// R16's dispatch-cuts both neutral -> the invariant ~124us build cost is the
// ~3.2M sub-cache-line scattered writes (tmp fill + pairs fill), each a 64B
// line RMW at the ~2TB/s random-line service rate. Fix: stage in LDS, write
// coalesced runs.
//  * bucket_scatter_lds (CHUNK=8192, 196 blocks): chunk -> LDS hist -> LDS
//    scan -> LDS scatter (32KB stage) -> per-wave streamed copy of each
//    bucket's contiguous run (avg 42 ints) to global. 1.6M 4B scatters ->
//    ~77k run-boundary partial lines.
//  * bucket_build_lds: sort the bucket's ~8.2k pairs fully in LDS (40KB
//    stage), stream out pairs[s..e) coalesced. Fallback to direct scatter if
//    a bucket exceeds stage (mean+22sigma -- never). cast_scale stays fused.
// Aggs: exact R11 config (proven 55.7/56.6us; gather plateau confirmed by 6
// failed configs). Pre-commit: if total stays ~236, remainder is fixed
// overhead -> roofline.

#define BKT_SHIFT 9
#define BKT_NODES 512
#define CHUNK 8192
#define STAGE_CAP 10240

typedef __attribute__((ext_vector_type(8))) _Float16 half8;
typedef __attribute__((ext_vector_type(4))) float float4v;
typedef __attribute__((ext_vector_type(4))) unsigned uint4v;

__device__ __forceinline__ int imin(int a, int b) { return a < b ? a : b; }
__device__ __forceinline__ int imax(int a, int b) { return a > b ? a : b; }
__device__ __forceinline__ unsigned h2u(__half2 v) {
  union { __half2 h; unsigned u; } c; c.h = v; return c.u;
}
__device__ __forceinline__ __half2 u2h(unsigned x) {
  union { unsigned u; __half2 h; } c; c.u = x; return c.h;
}

// ---------------- A0: per-chunk bucket histogram ---------------------------
// cnt[bucket*nblk + chunk] (bucket-major). Dual sub-histograms, int4 loads.
__global__ __launch_bounds__(256) void bucket_count(const int* __restrict__ dst,
                                                    int* __restrict__ cnt,
                                                    int E, int nbk, int nblk) {
  __shared__ int hist[2][256];
  const int t = threadIdx.x;
  const int h = (t >> 7) & 1;
  hist[0][t] = 0;
  hist[1][t] = 0;
  __syncthreads();
  const int base = blockIdx.x * CHUNK;
  const int end = imin(base + CHUNK, E);
  for (int e = base + t * 4; e < end; e += 1024) {
    if (e + 3 < end) {
      const int4 d4 = *(const int4*)(dst + e);
      atomicAdd(&hist[h][d4.x >> BKT_SHIFT], 1);
      atomicAdd(&hist[h][d4.y >> BKT_SHIFT], 1);
      atomicAdd(&hist[h][d4.z >> BKT_SHIFT], 1);
      atomicAdd(&hist[h][d4.w >> BKT_SHIFT], 1);
    } else {
      for (int k = e; k < end; ++k) atomicAdd(&hist[h][dst[k] >> BKT_SHIFT], 1);
    }
  }
  __syncthreads();
  if (t < nbk) cnt[t * nblk + blockIdx.x] = hist[0][t] + hist[1][t];
}

// ---------------- A1: per-bucket row scan (in place), nblk <= 256 ----------
__global__ __launch_bounds__(256) void scan_rows(int* __restrict__ cnt,
                                                 int* __restrict__ rowsum,
                                                 int nbk, int nblk) {
  __shared__ int red[256];
  const int b = blockIdx.x;
  const int t = threadIdx.x;
  const int v = (t < nblk) ? cnt[b * nblk + t] : 0;
  red[t] = v;
  __syncthreads();
  for (int off = 1; off < 256; off <<= 1) {
    const int u = (t >= off) ? red[t - off] : 0;
    __syncthreads();
    red[t] += u;
    __syncthreads();
  }
  if (t < nblk) cnt[b * nblk + t] = red[t] - v;  // within-row exclusive
  if (t == 255) rowsum[b] = red[255];
}

// ---------------- A2: LDS-staged scatter (line-granular writes) ------------
// tmp entry packed: (src << 9) | (dst & 511)  [src < 2^17 for N=100k].
// Per block: chunk -> LDS hist -> scan -> LDS scatter stage -> per-wave
// streamed copy of each bucket's contiguous run to tmp[gofs[b]..].
__global__ __launch_bounds__(512) void bucket_scatter(const int* __restrict__ src,
                                                      const int* __restrict__ dst,
                                                      const int* __restrict__ cnt,
                                                      const int* __restrict__ rowsum,
                                                      int* __restrict__ tmp,
                                                      int E, int nbk, int nblk) {
  __shared__ int hist[2][256];
  __shared__ int lofs[256];
  __shared__ int gofs[256];
  __shared__ int cur[256];
  __shared__ int red[256];
  __shared__ int stage[CHUNK];
  const int t = threadIdx.x;
  const int c = blockIdx.x;
  hist[t >> 8][t & 255] = 0;
  __syncthreads();
  const int h = (t >> 8) & 1;
  const int base = c * CHUNK;
  const int end = imin(base + CHUNK, E);
  // phase 1: local histogram
  for (int e = base + t * 4; e < end; e += 2048) {
    if (e + 3 < end) {
      const int4 d4 = *(const int4*)(dst + e);
      atomicAdd(&hist[h][d4.x >> BKT_SHIFT], 1);
      atomicAdd(&hist[h][d4.y >> BKT_SHIFT], 1);
      atomicAdd(&hist[h][d4.z >> BKT_SHIFT], 1);
      atomicAdd(&hist[h][d4.w >> BKT_SHIFT], 1);
    } else {
      for (int k = e; k < end; ++k) atomicAdd(&hist[h][dst[k] >> BKT_SHIFT], 1);
    }
  }
  __syncthreads();
  // phase 2a: local exclusive scan of bucket counts
  int tot = 0;
  if (t < 256) {
    tot = hist[0][t] + hist[1][t];
    red[t] = tot;
  }
  __syncthreads();
  for (int off = 1; off < 256; off <<= 1) {
    int u = 0;
    if (t < 256 && t >= off) u = red[t - off];
    __syncthreads();
    if (t < 256) red[t] += u;
    __syncthreads();
  }
  if (t < 256) {
    lofs[t] = red[t] - tot;
    cur[t] = red[t] - tot;
  }
  __syncthreads();
  // phase 2b: global offsets = rowbase (local scan of rowsum) + cnt prefix
  int rv = 0;
  if (t < 256) {
    rv = (t < nbk) ? rowsum[t] : 0;
    red[t] = rv;
  }
  __syncthreads();
  for (int off = 1; off < 256; off <<= 1) {
    int u = 0;
    if (t < 256 && t >= off) u = red[t - off];
    __syncthreads();
    if (t < 256) red[t] += u;
    __syncthreads();
  }
  if (t < nbk) gofs[t] = (red[t] - rv) + cnt[t * nblk + c];
  __syncthreads();
  // phase 3: re-read (L2-hot) and scatter into LDS stage
  for (int e = base + t * 4; e < end; e += 2048) {
    if (e + 3 < end) {
      const int4 s4 = *(const int4*)(src + e);
      const int4 d4 = *(const int4*)(dst + e);
      int p0 = atomicAdd(&cur[d4.x >> BKT_SHIFT], 1);
      stage[p0] = (s4.x << 9) | (d4.x & 511);
      int p1 = atomicAdd(&cur[d4.y >> BKT_SHIFT], 1);
      stage[p1] = (s4.y << 9) | (d4.y & 511);
      int p2 = atomicAdd(&cur[d4.z >> BKT_SHIFT], 1);
      stage[p2] = (s4.z << 9) | (d4.z & 511);
      int p3 = atomicAdd(&cur[d4.w >> BKT_SHIFT], 1);
      stage[p3] = (s4.w << 9) | (d4.w & 511);
    } else {
      for (int k = e; k < end; ++k) {
        const int d = dst[k];
        const int pos = atomicAdd(&cur[d >> BKT_SHIFT], 1);
        stage[pos] = (src[k] << 9) | (d & 511);
      }
    }
  }
  __syncthreads();
  // phase 4: stream each bucket's run out coalesced (wave per bucket)
  const int wv = t >> 6, lane = t & 63;
  for (int b = wv; b < nbk; b += 8) {
    const int len = hist[0][b] + hist[1][b];
    const int lo = lofs[b];
    const int go = gofs[b];
    for (int k = lane; k < len; k += 64) tmp[go + k] = stage[lo + k];
  }
}

// ---------------- B: per-bucket CSR build, LDS-sorted, + fused cast --------
// 1024 threads/block. Local rowbase scan -> LDS node histogram -> 512-wide
// scan -> row_ptr -> LDS-sorted pairs stage -> coalesced stream-out -> fused
// xs cast (dinv stashed in LDS). Fallback to direct scatter if len>STAGE_CAP.
__global__ __launch_bounds__(1024) void bucket_build(const int* __restrict__ tmp,
                                                     const int* __restrict__ rowsum,
                                                     int* __restrict__ row_ptr,
                                                     int* __restrict__ pairs,
                                                     const float* __restrict__ x,
                                                     __half* __restrict__ xs,
                                                     __half* __restrict__ hs,
                                                     int n, int nbk, int E) {
  __shared__ int hist[BKT_NODES];
  __shared__ int scn[BKT_NODES];
  __shared__ int red[256];
  __shared__ int stage[STAGE_CAP];
  __shared__ int s_sh;
  const int b = blockIdx.x;
  const int t = threadIdx.x;
  const int node0 = b << BKT_SHIFT;
  int v0 = 0;
  if (t < 256) {
    v0 = (t < nbk) ? rowsum[t] : 0;
    red[t] = v0;
  }
  if (t < BKT_NODES) hist[t] = 0;
  __syncthreads();
  for (int off = 1; off < 256; off <<= 1) {
    int u = 0;
    if (t < 256 && t >= off) u = red[t - off];
    __syncthreads();
    if (t < 256) red[t] += u;
    __syncthreads();
  }
  if (t == 0) s_sh = red[b] - rowsum[b];  // exclusive sum through bucket b
  __syncthreads();
  const int s = s_sh;
  const int e = s + rowsum[b];
  const int len = e - s;
  for (int k = s + t; k < e; k += 1024) atomicAdd(&hist[tmp[k] & 511], 1);
  __syncthreads();
  int v = 0;
  if (t < BKT_NODES) {
    v = hist[t];
    scn[t] = v;
  }
  __syncthreads();
  for (int off = 1; off < BKT_NODES; off <<= 1) {
    int u = 0;
    if (t < BKT_NODES && t >= off) u = scn[t - off];
    __syncthreads();
    if (t < BKT_NODES) scn[t] += u;
    __syncthreads();
  }
  const bool staged = (len <= STAGE_CAP);
  if (t < BKT_NODES) {
    const int lexcl = scn[t] - v;  // local (0-based) exclusive prefix
    const int node = node0 + t;
    if (node < n) row_ptr[node] = s + lexcl;
    if (b == nbk - 1 && t == 0) row_ptr[n] = E;
    hist[t] = staged ? lexcl : (s + lexcl);           // cursor (local/global)
    scn[t] = __float_as_int(rsqrtf(1.0f + (float)v)); // stash dinv for cast
  }
  __syncthreads();
  if (staged) {
    // sort into LDS, then stream out coalesced
    for (int k = s + t; k < e; k += 1024) {
      const int w = tmp[k];
      const int pos = atomicAdd(&hist[w & 511], 1);
      stage[pos] = w >> 9;
    }
    __syncthreads();
    for (int k = t; k < len; k += 1024) pairs[s + k] = stage[k];
  } else {
    for (int k = s + t; k < e; k += 1024) {
      const int w = tmp[k];
      const int pos = atomicAdd(&hist[w & 511], 1);
      pairs[pos] = w >> 9;
    }
  }
  // ---- fused cast_scale: xs[node] = dinv[node] * x[node] (fp16) ----
  const int nloc = imin(BKT_NODES, n - node0);
  for (int idx = t; idx < nloc * 16; idx += 1024) {
    const int nl = idx >> 4, f4 = idx & 15;
    const float4 v4 = ((const float4*)x)[(size_t)(node0 + nl) * 16 + f4];
    const float d = __int_as_float(scn[nl]);
    __half2* o = (__half2*)(xs + (size_t)(node0 + nl) * 64 + f4 * 4);
    o[0] = __floats2half2_rn(d * v4.x, d * v4.y);
    o[1] = __floats2half2_rn(d * v4.z, d * v4.w);
  }
  // sentinel rows (xs[n], hs[n] = 0); hs aliases tmp but row n sits at byte
  // offset n*128 (12.8MB) > E*4 (6.4MB), so no clash with live tmp data.
  if (b == 0 && t < 32) {
    if (t < 16)
      ((float2*)(xs + (size_t)n * 64))[t] = make_float2(0.f, 0.f);
    else
      ((float2*)(hs + (size_t)n * 64))[t - 16] = make_float2(0.f, 0.f);
  }
}

// ---------------- aggregation + fused dense via MFMA (R8/R11 config) -------
// Wave handles 16 rows (4 groups of 4 rows interleaved). Per row: 8 edge
// slots (lane=8g+q, 16B of 8 halves/lane), packed-half2 accumulate; 4 rows'
// pairs-prefetch + gather chains run concurrently. One xor-32 fold (slots
// 8->4), self-term on g==0, di-scale, store to wave-private LDS A-tile
// ylds[row][(g&3)*64 + 8q+c] (K'=256; last 4-slot reduction rides the MFMA
// K-dim, B = W replicated over the 4 slots). 8 k-steps x 4 n-tiles of
// mfma_f32_16x16x32_f16, bias in C-init.
// A layout: A[m=lane&15][k=(lane>>4)*8+j]; C/D: col=lane&15, row=quad*4+reg.

#define YSTRIDE 264  // 256 + 8 halves pad

__global__ __launch_bounds__(256, 4) void agg_layer1(const __half* __restrict__ xs,
                                                     const int* __restrict__ pairs,
                                                     const int* __restrict__ row_ptr,
                                                     const float* __restrict__ W1,
                                                     const float* __restrict__ b1,
                                                     __half* __restrict__ hs, int n) {
  __shared__ _Float16 ylds_all[4][16 * YSTRIDE];
  __shared__ float dilds_all[4][16];
  const int wv = threadIdx.x >> 6;
  _Float16* ylds = ylds_all[wv];
  float* dilds = dilds_all[wv];
  const int lane = threadIdx.x & 63;
  const int g = lane >> 3, q = lane & 7;
  const int quad = lane >> 4, col = lane & 15;

  // B-fragments: k = s2*32 + quad*8 + jj; feature = k & 63 -> sW = s2 & 1.
  half8 bfrag[2][4];
#pragma unroll
  for (int s = 0; s < 2; ++s)
#pragma unroll
    for (int t = 0; t < 4; ++t)
#pragma unroll
      for (int jj = 0; jj < 8; ++jj)
        bfrag[s][t][jj] = (_Float16)W1[(s * 32 + quad * 8 + jj) * 64 + t * 16 + col];
  float bias[4];
#pragma unroll
  for (int t = 0; t < 4; ++t) bias[t] = b1[t * 16 + col];

  const int ntiles = (n + 15) >> 4;
  for (int tile = blockIdx.x * 4 + wv; tile < ntiles; tile += gridDim.x * 4) {
    const int row0 = tile << 4;
#pragma unroll 1
    for (int rg = 0; rg < 4; ++rg) {  // 4 rows interleaved per group
      int start[4], end[4], idx[4];
      __half2 acc[4][4];
      int maxdeg = 0;
#pragma unroll
      for (int j = 0; j < 4; ++j) {
        const int i = row0 + rg * 4 + j;
        start[j] = 0; end[j] = 0;
        if (i < n) { start[j] = row_ptr[i]; end[j] = row_ptr[i + 1]; }
        maxdeg = imax(maxdeg, end[j] - start[j]);
#pragma unroll
        for (int k = 0; k < 4; ++k) acc[j][k] = u2h(0u);
        idx[j] = (start[j] + g < end[j]) ? pairs[start[j] + g] : n;
      }
      const int iters = (maxdeg + 7) >> 3;
#pragma unroll 1
      for (int it = 0; it < iters; ++it) {
        int nidx[4];
#pragma unroll
        for (int j = 0; j < 4; ++j) {
          const int ofs2 = start[j] + (it + 1) * 8 + g;
          nidx[j] = (ofs2 < end[j]) ? pairs[ofs2] : n;
        }
#pragma unroll
        for (int j = 0; j < 4; ++j) {
          const float4 rr = *(const float4*)(xs + (size_t)idx[j] * 64 + q * 8);
          const __half2* hp = (const __half2*)&rr;
#pragma unroll
          for (int k = 0; k < 4; ++k) acc[j][k] = __hadd2(acc[j][k], hp[k]);
        }
#pragma unroll
        for (int j = 0; j < 4; ++j) idx[j] = nidx[j];
      }
#pragma unroll
      for (int j = 0; j < 4; ++j) {
        const int i = row0 + rg * 4 + j;
        // self term (once, on g==0 lanes)
        if (g == 0 && i < n) {
          const float4 sr = *(const float4*)(xs + (size_t)i * 64 + q * 8);
          const __half2* hp = (const __half2*)&sr;
#pragma unroll
          for (int k = 0; k < 4; ++k) acc[j][k] = __hadd2(acc[j][k], hp[k]);
        }
        // fold slots g and g^4 (lane xor 32)
#pragma unroll
        for (int k = 0; k < 4; ++k) {
          unsigned u = __shfl_xor(h2u(acc[j][k]), 32);
          acc[j][k] = __hadd2(acc[j][k], u2h(u));
        }
        const float di = rsqrtf((float)(1 + end[j] - start[j]));
        const __half hdi = __float2half(di);
        const __half2 di2 = __halves2half2(hdi, hdi);
        uint4v st;
        st.x = h2u(__hmul2(di2, acc[j][0]));
        st.y = h2u(__hmul2(di2, acc[j][1]));
        st.z = h2u(__hmul2(di2, acc[j][2]));
        st.w = h2u(__hmul2(di2, acc[j][3]));
        *(uint4v*)(ylds + (rg * 4 + j) * YSTRIDE + (g & 3) * 64 + q * 8) = st;
        if (lane == 0) dilds[rg * 4 + j] = di;
      }
    }
    // MFMA: D = A(16x256) * B'(256x64) + bias
    float4v acc[4];
#pragma unroll
    for (int t = 0; t < 4; ++t) acc[t] = (float4v){bias[t], bias[t], bias[t], bias[t]};
#pragma unroll
    for (int s2 = 0; s2 < 8; ++s2) {
      half8 af = *(half8*)(ylds + col * YSTRIDE + s2 * 32 + quad * 8);
      const int sW = s2 & 1;
#pragma unroll
      for (int t = 0; t < 4; ++t)
        acc[t] = __builtin_amdgcn_mfma_f32_16x16x32_f16(af, bfrag[sW][t], acc[t], 0, 0, 0);
    }
    const float4 dis = *(const float4*)(dilds + quad * 4);
    const float dd[4] = {dis.x, dis.y, dis.z, dis.w};
#pragma unroll
    for (int t = 0; t < 4; ++t)
#pragma unroll
      for (int reg = 0; reg < 4; ++reg) {
        const int row = row0 + quad * 4 + reg;
        if (row < n)
          hs[(size_t)row * 64 + t * 16 + col] =
              __float2half(dd[reg] * fmaxf(acc[t][reg], 0.f));
      }
  }
}

// Layer 2: same structure; B' = [Wmu | Wlv] (64 cols), fp32 outputs.
__global__ __launch_bounds__(256, 4) void agg_layer2(const __half* __restrict__ hsin,
                                                     const int* __restrict__ pairs,
                                                     const int* __restrict__ row_ptr,
                                                     const float* __restrict__ Wmu,
                                                     const float* __restrict__ bmu,
                                                     const float* __restrict__ Wlv,
                                                     const float* __restrict__ blv,
                                                     float* __restrict__ out_mu,
                                                     float* __restrict__ out_lv, int n) {
  __shared__ _Float16 ylds_all[4][16 * YSTRIDE];
  const int wv = threadIdx.x >> 6;
  _Float16* ylds = ylds_all[wv];
  const int lane = threadIdx.x & 63;
  const int g = lane >> 3, q = lane & 7;
  const int quad = lane >> 4, col = lane & 15;

  half8 bfrag[2][4];
#pragma unroll
  for (int s = 0; s < 2; ++s)
#pragma unroll
    for (int t = 0; t < 4; ++t) {
      const int j = t * 16 + col;
      const float* W = (j < 32) ? Wmu : Wlv;
      const int jc = j & 31;
#pragma unroll
      for (int jj = 0; jj < 8; ++jj)
        bfrag[s][t][jj] = (_Float16)W[(s * 32 + quad * 8 + jj) * 32 + jc];
    }
  float bias[4];
#pragma unroll
  for (int t = 0; t < 4; ++t) {
    const int j = t * 16 + col;
    bias[t] = (j < 32) ? bmu[j] : blv[j - 32];
  }

  const int ntiles = (n + 15) >> 4;
  for (int tile = blockIdx.x * 4 + wv; tile < ntiles; tile += gridDim.x * 4) {
    const int row0 = tile << 4;
#pragma unroll 1
    for (int rg = 0; rg < 4; ++rg) {
      int start[4], end[4], idx[4];
      __half2 acc[4][4];
      int maxdeg = 0;
#pragma unroll
      for (int j = 0; j < 4; ++j) {
        const int i = row0 + rg * 4 + j;
        start[j] = 0; end[j] = 0;
        if (i < n) { start[j] = row_ptr[i]; end[j] = row_ptr[i + 1]; }
        maxdeg = imax(maxdeg, end[j] - start[j]);
#pragma unroll
        for (int k = 0; k < 4; ++k) acc[j][k] = u2h(0u);
        idx[j] = (start[j] + g < end[j]) ? pairs[start[j] + g] : n;
      }
      const int iters = (maxdeg + 7) >> 3;
#pragma unroll 1
      for (int it = 0; it < iters; ++it) {
        int nidx[4];
#pragma unroll
        for (int j = 0; j < 4; ++j) {
          const int ofs2 = start[j] + (it + 1) * 8 + g;
          nidx[j] = (ofs2 < end[j]) ? pairs[ofs2] : n;
        }
#pragma unroll
        for (int j = 0; j < 4; ++j) {
          const float4 rr = *(const float4*)(hsin + (size_t)idx[j] * 64 + q * 8);
          const __half2* hp = (const __half2*)&rr;
#pragma unroll
          for (int k = 0; k < 4; ++k) acc[j][k] = __hadd2(acc[j][k], hp[k]);
        }
#pragma unroll
        for (int j = 0; j < 4; ++j) idx[j] = nidx[j];
      }
#pragma unroll
      for (int j = 0; j < 4; ++j) {
        const int i = row0 + rg * 4 + j;
        if (g == 0 && i < n) {
          const float4 sr = *(const float4*)(hsin + (size_t)i * 64 + q * 8);
          const __half2* hp = (const __half2*)&sr;
#pragma unroll
          for (int k = 0; k < 4; ++k) acc[j][k] = __hadd2(acc[j][k], hp[k]);
        }
#pragma unroll
        for (int k = 0; k < 4; ++k) {
          unsigned u = __shfl_xor(h2u(acc[j][k]), 32);
          acc[j][k] = __hadd2(acc[j][k], u2h(u));
        }
        const float di = rsqrtf((float)(1 + end[j] - start[j]));
        const __half hdi = __float2half(di);
        const __half2 di2 = __halves2half2(hdi, hdi);
        uint4v st;
        st.x = h2u(__hmul2(di2, acc[j][0]));
        st.y = h2u(__hmul2(di2, acc[j][1]));
        st.z = h2u(__hmul2(di2, acc[j][2]));
        st.w = h2u(__hmul2(di2, acc[j][3]));
        *(uint4v*)(ylds + (rg * 4 + j) * YSTRIDE + (g & 3) * 64 + q * 8) = st;
      }
    }
    float4v acc[4];
#pragma unroll
    for (int t = 0; t < 4; ++t) acc[t] = (float4v){bias[t], bias[t], bias[t], bias[t]};
#pragma unroll
    for (int s2 = 0; s2 < 8; ++s2) {
      half8 af = *(half8*)(ylds + col * YSTRIDE + s2 * 32 + quad * 8);
      const int sW = s2 & 1;
#pragma unroll
      for (int t = 0; t < 4; ++t)
        acc[t] = __builtin_amdgcn_mfma_f32_16x16x32_f16(af, bfrag[sW][t], acc[t], 0, 0, 0);
    }
#pragma unroll
    for (int t = 0; t < 4; ++t)
#pragma unroll
      for (int reg = 0; reg < 4; ++reg) {
        const int row = row0 + quad * 4 + reg;
        if (row < n) {
          const int j = t * 16 + col;
          if (j < 32)
            out_mu[(size_t)row * 32 + j] = acc[t][reg];
          else
            out_lv[(size_t)row * 32 + (j - 32)] = acc[t][reg];
        }
      }
  }
}

extern "C" void kernel_launch(void* const* d_in, const int* in_sizes, int n_in,
                              void* d_out, int out_size, void* d_ws, size_t ws_size,
                              hipStream_t stream) {
  const float* x = (const float*)d_in[0];
  const int* ei = (const int*)d_in[1];  // [2, E] row-major int32
  const float* W1 = (const float*)d_in[2];
  const float* b1 = (const float*)d_in[3];
  const float* Wmu = (const float*)d_in[4];
  const float* bmu = (const float*)d_in[5];
  const float* Wlv = (const float*)d_in[6];
  const float* blv = (const float*)d_in[7];

  const int N = in_sizes[0] / 64;
  const int E = in_sizes[1] / 2;
  const int* src = ei;
  const int* dst = ei + E;

  const int NBK = (N + BKT_NODES - 1) >> BKT_SHIFT;  // 196 buckets (<=256)
  const int NBLK = (E + CHUNK - 1) / CHUNK;          // 196 chunks (<=256)
  const int FL = NBK * NBLK;                         // ~38k

  auto align256 = [](size_t v) { return (v + 255) & ~(size_t)255; };
  char* p = (char*)d_ws;
  int* row_ptr = (int*)p;  p += align256((size_t)(N + 1) * 4);
  int* rowsum = (int*)p;   p += align256((size_t)256 * 4);
  int* cnt = (int*)p;      p += align256((size_t)FL * 4);
  int* pairs = (int*)p;    p += align256((size_t)E * 4);
  __half* xs = (__half*)p; p += align256((size_t)(N + 1) * 64 * 2);
  size_t tmp_bytes = (size_t)E * 4;  // packed int
  size_t hs_bytes = (size_t)(N + 1) * 64 * 2;
  int* tmp = (int*)p;      // union: tmp dead after bucket_build; hs written later
  __half* hs = (__half*)p;
  p += align256(tmp_bytes > hs_bytes ? tmp_bytes : hs_bytes);

  float* out_mu = (float*)d_out;
  float* out_lv = out_mu + (size_t)N * 32;

  // --- CSR build: 4 plain dispatches, LDS-staged line-granular writes ---
  bucket_count<<<NBLK, 256, 0, stream>>>(dst, cnt, E, NBK, NBLK);
  scan_rows<<<NBK, 256, 0, stream>>>(cnt, rowsum, NBK, NBLK);
  bucket_scatter<<<NBLK, 512, 0, stream>>>(src, dst, cnt, rowsum, tmp, E, NBK, NBLK);
  bucket_build<<<NBK, 1024, 0, stream>>>(tmp, rowsum, row_ptr, pairs, x, xs, hs,
                                         N, NBK, E);

  // --- aggregation + fused dense layers (MFMA epilogue) ---
  const int ntiles = (N + 15) / 16;
  const int ablocks = (ntiles + 3) / 4;  // 1 tile (16 rows) per wave
  agg_layer1<<<ablocks, 256, 0, stream>>>(xs, pairs, row_ptr, W1, b1, hs, N);
  agg_layer2<<<ablocks, 256, 0, stream>>>(hs, pairs, row_ptr, Wmu, bmu, Wlv, blv,
                                          out_mu, out_lv, N);
}

// Round 7
// 224.397 us; speedup vs baseline: 2.8878x; 1.0230x over previous
//
#include <hip/hip_runtime.h>
#include <hip/hip_fp16.h>

// GCN VGAE encoder:
//   h  = relu((A @ x) @ W1 + b1)          [associativity: A(xW) == (Ax)W]
//   mu = (A @ h) @ Wmu + bmu ; lv = (A @ h) @ Wlv + blv
// A = D^-1/2 (Adj + I) D^-1/2, deg on dst side. dinv folded into tables:
//   xs[s]=dinv_s*x[s]; hs[i]=dinv_i*relu(...); y_i = dinv_i*(sum_e xs[src]+xs[i])
//
// R18: build-side CONCURRENCY. R17's staged writes won +12us; remaining
// ~110us build vs ~30us throughput-roofline points at latency-boundedness:
// all build kernels ran 196 blocks = 1 block/CU (4-16 waves, 60 CUs idle).
//  * CHUNK 8192->4096: count/scatter at 391 blocks (~1.5/CU); bucket_count
//    512 threads. 3-4x resident waves on both edge passes.
//  * cast_scale UN-fused (R11's note: fusion serializes the build tail;
//    reintroduced by me in R15 -- reverted). bucket_build writes dinv; the
//    38MB cast runs as a 6255-block chip-filling kernel (~8us).
//  * keep R17's LDS-staged scatter + staged pairs sort (line-granular).
// Aggs: exact R11 config (gather plateau, 7 configs). Pre-commit: if total
// >=225us, build is at its structural floor -> declare roofline.

#define BKT_SHIFT 9
#define BKT_NODES 512
#define CHUNK 4096
#define STAGE_CAP 10240

typedef __attribute__((ext_vector_type(8))) _Float16 half8;
typedef __attribute__((ext_vector_type(4))) float float4v;
typedef __attribute__((ext_vector_type(4))) unsigned uint4v;

__device__ __forceinline__ int imin(int a, int b) { return a < b ? a : b; }
__device__ __forceinline__ int imax(int a, int b) { return a > b ? a : b; }
__device__ __forceinline__ unsigned h2u(__half2 v) {
  union { __half2 h; unsigned u; } c; c.h = v; return c.u;
}
__device__ __forceinline__ __half2 u2h(unsigned x) {
  union { unsigned u; __half2 h; } c; c.u = x; return c.h;
}

// ---------------- A0: per-chunk bucket histogram (512 thr, 391 blocks) -----
__global__ __launch_bounds__(512) void bucket_count(const int* __restrict__ dst,
                                                    int* __restrict__ cnt,
                                                    int E, int nbk, int nblk) {
  __shared__ int hist[2][256];
  const int t = threadIdx.x;
  hist[t >> 8][t & 255] = 0;
  __syncthreads();
  const int h = (t >> 8) & 1;  // waves 0-3 -> copy 0, waves 4-7 -> copy 1
  const int base = blockIdx.x * CHUNK;
  const int end = imin(base + CHUNK, E);
  for (int e = base + t * 4; e < end; e += 2048) {
    if (e + 3 < end) {
      const int4 d4 = *(const int4*)(dst + e);
      atomicAdd(&hist[h][d4.x >> BKT_SHIFT], 1);
      atomicAdd(&hist[h][d4.y >> BKT_SHIFT], 1);
      atomicAdd(&hist[h][d4.z >> BKT_SHIFT], 1);
      atomicAdd(&hist[h][d4.w >> BKT_SHIFT], 1);
    } else {
      for (int k = e; k < end; ++k) atomicAdd(&hist[h][dst[k] >> BKT_SHIFT], 1);
    }
  }
  __syncthreads();
  if (t < nbk) cnt[t * nblk + blockIdx.x] = hist[0][t] + hist[1][t];
}

// ---------------- A1: per-bucket row scan (in place), nblk <= 512 ----------
__global__ __launch_bounds__(256) void scan_rows(int* __restrict__ cnt,
                                                 int* __restrict__ rowsum,
                                                 int nbk, int nblk) {
  __shared__ int red[256];
  const int b = blockIdx.x;
  const int t = threadIdx.x;
  const int rbase = b * nblk;
  const int i0 = 2 * t, i1 = 2 * t + 1;
  const int v0 = (i0 < nblk) ? cnt[rbase + i0] : 0;
  const int v1 = (i1 < nblk) ? cnt[rbase + i1] : 0;
  const int run = v0 + v1;
  red[t] = run;
  __syncthreads();
  for (int off = 1; off < 256; off <<= 1) {
    const int u = (t >= off) ? red[t - off] : 0;
    __syncthreads();
    red[t] += u;
    __syncthreads();
  }
  const int acc = red[t] - run;  // exclusive prefix of this thread's span
  if (t == 255) rowsum[b] = red[255];
  if (i0 < nblk) cnt[rbase + i0] = acc;
  if (i1 < nblk) cnt[rbase + i1] = acc + v0;
}

// ---------------- A2: LDS-staged scatter (line-granular writes) ------------
// tmp entry packed: (src << 9) | (dst & 511)  [src < 2^17 for N=100k].
__global__ __launch_bounds__(512) void bucket_scatter(const int* __restrict__ src,
                                                      const int* __restrict__ dst,
                                                      const int* __restrict__ cnt,
                                                      const int* __restrict__ rowsum,
                                                      int* __restrict__ tmp,
                                                      int E, int nbk, int nblk) {
  __shared__ int hist[2][256];
  __shared__ int lofs[256];
  __shared__ int gofs[256];
  __shared__ int cur[256];
  __shared__ int red[256];
  __shared__ int stage[CHUNK];
  const int t = threadIdx.x;
  const int c = blockIdx.x;
  hist[t >> 8][t & 255] = 0;
  __syncthreads();
  const int h = (t >> 8) & 1;
  const int base = c * CHUNK;
  const int end = imin(base + CHUNK, E);
  // phase 1: local histogram
  for (int e = base + t * 4; e < end; e += 2048) {
    if (e + 3 < end) {
      const int4 d4 = *(const int4*)(dst + e);
      atomicAdd(&hist[h][d4.x >> BKT_SHIFT], 1);
      atomicAdd(&hist[h][d4.y >> BKT_SHIFT], 1);
      atomicAdd(&hist[h][d4.z >> BKT_SHIFT], 1);
      atomicAdd(&hist[h][d4.w >> BKT_SHIFT], 1);
    } else {
      for (int k = e; k < end; ++k) atomicAdd(&hist[h][dst[k] >> BKT_SHIFT], 1);
    }
  }
  __syncthreads();
  // phase 2a: local exclusive scan of bucket counts
  int tot = 0;
  if (t < 256) {
    tot = hist[0][t] + hist[1][t];
    red[t] = tot;
  }
  __syncthreads();
  for (int off = 1; off < 256; off <<= 1) {
    int u = 0;
    if (t < 256 && t >= off) u = red[t - off];
    __syncthreads();
    if (t < 256) red[t] += u;
    __syncthreads();
  }
  if (t < 256) {
    lofs[t] = red[t] - tot;
    cur[t] = red[t] - tot;
  }
  __syncthreads();
  // phase 2b: global offsets = rowbase (local scan of rowsum) + cnt prefix
  int rv = 0;
  if (t < 256) {
    rv = (t < nbk) ? rowsum[t] : 0;
    red[t] = rv;
  }
  __syncthreads();
  for (int off = 1; off < 256; off <<= 1) {
    int u = 0;
    if (t < 256 && t >= off) u = red[t - off];
    __syncthreads();
    if (t < 256) red[t] += u;
    __syncthreads();
  }
  if (t < nbk) gofs[t] = (red[t] - rv) + cnt[t * nblk + c];
  __syncthreads();
  // phase 3: re-read (L2-hot) and scatter into LDS stage
  for (int e = base + t * 4; e < end; e += 2048) {
    if (e + 3 < end) {
      const int4 s4 = *(const int4*)(src + e);
      const int4 d4 = *(const int4*)(dst + e);
      int p0 = atomicAdd(&cur[d4.x >> BKT_SHIFT], 1);
      stage[p0] = (s4.x << 9) | (d4.x & 511);
      int p1 = atomicAdd(&cur[d4.y >> BKT_SHIFT], 1);
      stage[p1] = (s4.y << 9) | (d4.y & 511);
      int p2 = atomicAdd(&cur[d4.z >> BKT_SHIFT], 1);
      stage[p2] = (s4.z << 9) | (d4.z & 511);
      int p3 = atomicAdd(&cur[d4.w >> BKT_SHIFT], 1);
      stage[p3] = (s4.w << 9) | (d4.w & 511);
    } else {
      for (int k = e; k < end; ++k) {
        const int d = dst[k];
        const int pos = atomicAdd(&cur[d >> BKT_SHIFT], 1);
        stage[pos] = (src[k] << 9) | (d & 511);
      }
    }
  }
  __syncthreads();
  // phase 4: stream each bucket's run out (dense runs combine in L2)
  const int wv = t >> 6, lane = t & 63;
  for (int b = wv; b < nbk; b += 8) {
    const int len = hist[0][b] + hist[1][b];
    const int lo = lofs[b];
    const int go = gofs[b];
    for (int k = lane; k < len; k += 64) tmp[go + k] = stage[lo + k];
  }
}

// ---------------- B: per-bucket CSR build (LDS-sorted pairs) ---------------
// 1024 threads/block, 196 blocks. Local rowbase scan -> LDS node histogram ->
// 512-wide scan -> row_ptr/dinv (coalesced) -> LDS-sorted pairs stage ->
// coalesced stream-out. Fallback to direct scatter if len>STAGE_CAP.
__global__ __launch_bounds__(1024) void bucket_build(const int* __restrict__ tmp,
                                                     const int* __restrict__ rowsum,
                                                     int* __restrict__ row_ptr,
                                                     float* __restrict__ dinv,
                                                     int* __restrict__ pairs,
                                                     int n, int nbk, int E) {
  __shared__ int hist[BKT_NODES];
  __shared__ int scn[BKT_NODES];
  __shared__ int red[256];
  __shared__ int stage[STAGE_CAP];
  __shared__ int s_sh;
  const int b = blockIdx.x;
  const int t = threadIdx.x;
  const int node0 = b << BKT_SHIFT;
  int v0 = 0;
  if (t < 256) {
    v0 = (t < nbk) ? rowsum[t] : 0;
    red[t] = v0;
  }
  if (t < BKT_NODES) hist[t] = 0;
  __syncthreads();
  for (int off = 1; off < 256; off <<= 1) {
    int u = 0;
    if (t < 256 && t >= off) u = red[t - off];
    __syncthreads();
    if (t < 256) red[t] += u;
    __syncthreads();
  }
  if (t == 0) s_sh = red[b] - rowsum[b];  // exclusive sum through bucket b
  __syncthreads();
  const int s = s_sh;
  const int e = s + rowsum[b];
  const int len = e - s;
  for (int k = s + t; k < e; k += 1024) atomicAdd(&hist[tmp[k] & 511], 1);
  __syncthreads();
  int v = 0;
  if (t < BKT_NODES) {
    v = hist[t];
    scn[t] = v;
  }
  __syncthreads();
  for (int off = 1; off < BKT_NODES; off <<= 1) {
    int u = 0;
    if (t < BKT_NODES && t >= off) u = scn[t - off];
    __syncthreads();
    if (t < BKT_NODES) scn[t] += u;
    __syncthreads();
  }
  const bool staged = (len <= STAGE_CAP);
  if (t < BKT_NODES) {
    const int lexcl = scn[t] - v;  // local (0-based) exclusive prefix
    const int node = node0 + t;
    if (node < n) {
      row_ptr[node] = s + lexcl;
      dinv[node] = rsqrtf(1.0f + (float)v);  // deg includes self-loop
    }
    if (b == nbk - 1 && t == 0) row_ptr[n] = E;
    hist[t] = staged ? lexcl : (s + lexcl);  // cursor (local/global)
  }
  __syncthreads();
  if (staged) {
    for (int k = s + t; k < e; k += 1024) {
      const int w = tmp[k];
      const int pos = atomicAdd(&hist[w & 511], 1);
      stage[pos] = w >> 9;
    }
    __syncthreads();
    for (int k = t; k < len; k += 1024) pairs[s + k] = stage[k];
  } else {
    for (int k = s + t; k < e; k += 1024) {
      const int w = tmp[k];
      const int pos = atomicAdd(&hist[w & 511], 1);
      pairs[pos] = w >> 9;
    }
  }
}

// ---------------- table prep (standalone, chip-filling: R11 shape) ---------
// xs[i] = dinv[i] * x[i] in fp16; zeros sentinel row `nrow` of xs and hs.
__global__ __launch_bounds__(256) void cast_scale(const float* __restrict__ x,
                                                  const float* __restrict__ dinv,
                                                  __half* __restrict__ xs,
                                                  __half* __restrict__ hs,
                                                  int n4, int nrow) {
  int i = blockIdx.x * blockDim.x + threadIdx.x;
  if (i < n4) {
    float4 v = ((const float4*)x)[i];
    float d = dinv[i >> 4];
    __half2* o = (__half2*)(xs + (size_t)i * 4);
    o[0] = __floats2half2_rn(d * v.x, d * v.y);
    o[1] = __floats2half2_rn(d * v.z, d * v.w);
  } else if (i < n4 + 32) {
    int j = i - n4;
    if (j < 16)
      ((float2*)(xs + (size_t)nrow * 64))[j] = make_float2(0.f, 0.f);
    else
      ((float2*)(hs + (size_t)nrow * 64))[j - 16] = make_float2(0.f, 0.f);
  }
}

// ---------------- aggregation + fused dense via MFMA (R8/R11 config) -------
// Wave handles 16 rows (4 groups of 4 rows interleaved). Per row: 8 edge
// slots (lane=8g+q, 16B of 8 halves/lane), packed-half2 accumulate; 4 rows'
// pairs-prefetch + gather chains run concurrently. One xor-32 fold (slots
// 8->4), self-term on g==0, di-scale, store to wave-private LDS A-tile
// ylds[row][(g&3)*64 + 8q+c] (K'=256; last 4-slot reduction rides the MFMA
// K-dim, B = W replicated over the 4 slots). 8 k-steps x 4 n-tiles of
// mfma_f32_16x16x32_f16, bias in C-init.
// A layout: A[m=lane&15][k=(lane>>4)*8+j]; C/D: col=lane&15, row=quad*4+reg.

#define YSTRIDE 264  // 256 + 8 halves pad

__global__ __launch_bounds__(256, 4) void agg_layer1(const __half* __restrict__ xs,
                                                     const int* __restrict__ pairs,
                                                     const int* __restrict__ row_ptr,
                                                     const float* __restrict__ W1,
                                                     const float* __restrict__ b1,
                                                     __half* __restrict__ hs, int n) {
  __shared__ _Float16 ylds_all[4][16 * YSTRIDE];
  __shared__ float dilds_all[4][16];
  const int wv = threadIdx.x >> 6;
  _Float16* ylds = ylds_all[wv];
  float* dilds = dilds_all[wv];
  const int lane = threadIdx.x & 63;
  const int g = lane >> 3, q = lane & 7;
  const int quad = lane >> 4, col = lane & 15;

  // B-fragments: k = s2*32 + quad*8 + jj; feature = k & 63 -> sW = s2 & 1.
  half8 bfrag[2][4];
#pragma unroll
  for (int s = 0; s < 2; ++s)
#pragma unroll
    for (int t = 0; t < 4; ++t)
#pragma unroll
      for (int jj = 0; jj < 8; ++jj)
        bfrag[s][t][jj] = (_Float16)W1[(s * 32 + quad * 8 + jj) * 64 + t * 16 + col];
  float bias[4];
#pragma unroll
  for (int t = 0; t < 4; ++t) bias[t] = b1[t * 16 + col];

  const int ntiles = (n + 15) >> 4;
  for (int tile = blockIdx.x * 4 + wv; tile < ntiles; tile += gridDim.x * 4) {
    const int row0 = tile << 4;
#pragma unroll 1
    for (int rg = 0; rg < 4; ++rg) {  // 4 rows interleaved per group
      int start[4], end[4], idx[4];
      __half2 acc[4][4];
      int maxdeg = 0;
#pragma unroll
      for (int j = 0; j < 4; ++j) {
        const int i = row0 + rg * 4 + j;
        start[j] = 0; end[j] = 0;
        if (i < n) { start[j] = row_ptr[i]; end[j] = row_ptr[i + 1]; }
        maxdeg = imax(maxdeg, end[j] - start[j]);
#pragma unroll
        for (int k = 0; k < 4; ++k) acc[j][k] = u2h(0u);
        idx[j] = (start[j] + g < end[j]) ? pairs[start[j] + g] : n;
      }
      const int iters = (maxdeg + 7) >> 3;
#pragma unroll 1
      for (int it = 0; it < iters; ++it) {
        int nidx[4];
#pragma unroll
        for (int j = 0; j < 4; ++j) {
          const int ofs2 = start[j] + (it + 1) * 8 + g;
          nidx[j] = (ofs2 < end[j]) ? pairs[ofs2] : n;
        }
#pragma unroll
        for (int j = 0; j < 4; ++j) {
          const float4 rr = *(const float4*)(xs + (size_t)idx[j] * 64 + q * 8);
          const __half2* hp = (const __half2*)&rr;
#pragma unroll
          for (int k = 0; k < 4; ++k) acc[j][k] = __hadd2(acc[j][k], hp[k]);
        }
#pragma unroll
        for (int j = 0; j < 4; ++j) idx[j] = nidx[j];
      }
#pragma unroll
      for (int j = 0; j < 4; ++j) {
        const int i = row0 + rg * 4 + j;
        // self term (once, on g==0 lanes)
        if (g == 0 && i < n) {
          const float4 sr = *(const float4*)(xs + (size_t)i * 64 + q * 8);
          const __half2* hp = (const __half2*)&sr;
#pragma unroll
          for (int k = 0; k < 4; ++k) acc[j][k] = __hadd2(acc[j][k], hp[k]);
        }
        // fold slots g and g^4 (lane xor 32)
#pragma unroll
        for (int k = 0; k < 4; ++k) {
          unsigned u = __shfl_xor(h2u(acc[j][k]), 32);
          acc[j][k] = __hadd2(acc[j][k], u2h(u));
        }
        const float di = rsqrtf((float)(1 + end[j] - start[j]));
        const __half hdi = __float2half(di);
        const __half2 di2 = __halves2half2(hdi, hdi);
        uint4v st;
        st.x = h2u(__hmul2(di2, acc[j][0]));
        st.y = h2u(__hmul2(di2, acc[j][1]));
        st.z = h2u(__hmul2(di2, acc[j][2]));
        st.w = h2u(__hmul2(di2, acc[j][3]));
        *(uint4v*)(ylds + (rg * 4 + j) * YSTRIDE + (g & 3) * 64 + q * 8) = st;
        if (lane == 0) dilds[rg * 4 + j] = di;
      }
    }
    // MFMA: D = A(16x256) * B'(256x64) + bias
    float4v acc[4];
#pragma unroll
    for (int t = 0; t < 4; ++t) acc[t] = (float4v){bias[t], bias[t], bias[t], bias[t]};
#pragma unroll
    for (int s2 = 0; s2 < 8; ++s2) {
      half8 af = *(half8*)(ylds + col * YSTRIDE + s2 * 32 + quad * 8);
      const int sW = s2 & 1;
#pragma unroll
      for (int t = 0; t < 4; ++t)
        acc[t] = __builtin_amdgcn_mfma_f32_16x16x32_f16(af, bfrag[sW][t], acc[t], 0, 0, 0);
    }
    const float4 dis = *(const float4*)(dilds + quad * 4);
    const float dd[4] = {dis.x, dis.y, dis.z, dis.w};
#pragma unroll
    for (int t = 0; t < 4; ++t)
#pragma unroll
      for (int reg = 0; reg < 4; ++reg) {
        const int row = row0 + quad * 4 + reg;
        if (row < n)
          hs[(size_t)row * 64 + t * 16 + col] =
              __float2half(dd[reg] * fmaxf(acc[t][reg], 0.f));
      }
  }
}

// Layer 2: same structure; B' = [Wmu | Wlv] (64 cols), fp32 outputs.
__global__ __launch_bounds__(256, 4) void agg_layer2(const __half* __restrict__ hsin,
                                                     const int* __restrict__ pairs,
                                                     const int* __restrict__ row_ptr,
                                                     const float* __restrict__ Wmu,
                                                     const float* __restrict__ bmu,
                                                     const float* __restrict__ Wlv,
                                                     const float* __restrict__ blv,
                                                     float* __restrict__ out_mu,
                                                     float* __restrict__ out_lv, int n) {
  __shared__ _Float16 ylds_all[4][16 * YSTRIDE];
  const int wv = threadIdx.x >> 6;
  _Float16* ylds = ylds_all[wv];
  const int lane = threadIdx.x & 63;
  const int g = lane >> 3, q = lane & 7;
  const int quad = lane >> 4, col = lane & 15;

  half8 bfrag[2][4];
#pragma unroll
  for (int s = 0; s < 2; ++s)
#pragma unroll
    for (int t = 0; t < 4; ++t) {
      const int j = t * 16 + col;
      const float* W = (j < 32) ? Wmu : Wlv;
      const int jc = j & 31;
#pragma unroll
      for (int jj = 0; jj < 8; ++jj)
        bfrag[s][t][jj] = (_Float16)W[(s * 32 + quad * 8 + jj) * 32 + jc];
    }
  float bias[4];
#pragma unroll
  for (int t = 0; t < 4; ++t) {
    const int j = t * 16 + col;
    bias[t] = (j < 32) ? bmu[j] : blv[j - 32];
  }

  const int ntiles = (n + 15) >> 4;
  for (int tile = blockIdx.x * 4 + wv; tile < ntiles; tile += gridDim.x * 4) {
    const int row0 = tile << 4;
#pragma unroll 1
    for (int rg = 0; rg < 4; ++rg) {
      int start[4], end[4], idx[4];
      __half2 acc[4][4];
      int maxdeg = 0;
#pragma unroll
      for (int j = 0; j < 4; ++j) {
        const int i = row0 + rg * 4 + j;
        start[j] = 0; end[j] = 0;
        if (i < n) { start[j] = row_ptr[i]; end[j] = row_ptr[i + 1]; }
        maxdeg = imax(maxdeg, end[j] - start[j]);
#pragma unroll
        for (int k = 0; k < 4; ++k) acc[j][k] = u2h(0u);
        idx[j] = (start[j] + g < end[j]) ? pairs[start[j] + g] : n;
      }
      const int iters = (maxdeg + 7) >> 3;
#pragma unroll 1
      for (int it = 0; it < iters; ++it) {
        int nidx[4];
#pragma unroll
        for (int j = 0; j < 4; ++j) {
          const int ofs2 = start[j] + (it + 1) * 8 + g;
          nidx[j] = (ofs2 < end[j]) ? pairs[ofs2] : n;
        }
#pragma unroll
        for (int j = 0; j < 4; ++j) {
          const float4 rr = *(const float4*)(hsin + (size_t)idx[j] * 64 + q * 8);
          const __half2* hp = (const __half2*)&rr;
#pragma unroll
          for (int k = 0; k < 4; ++k) acc[j][k] = __hadd2(acc[j][k], hp[k]);
        }
#pragma unroll
        for (int j = 0; j < 4; ++j) idx[j] = nidx[j];
      }
#pragma unroll
      for (int j = 0; j < 4; ++j) {
        const int i = row0 + rg * 4 + j;
        if (g == 0 && i < n) {
          const float4 sr = *(const float4*)(hsin + (size_t)i * 64 + q * 8);
          const __half2* hp = (const __half2*)&sr;
#pragma unroll
          for (int k = 0; k < 4; ++k) acc[j][k] = __hadd2(acc[j][k], hp[k]);
        }
#pragma unroll
        for (int k = 0; k < 4; ++k) {
          unsigned u = __shfl_xor(h2u(acc[j][k]), 32);
          acc[j][k] = __hadd2(acc[j][k], u2h(u));
        }
        const float di = rsqrtf((float)(1 + end[j] - start[j]));
        const __half hdi = __float2half(di);
        const __half2 di2 = __halves2half2(hdi, hdi);
        uint4v st;
        st.x = h2u(__hmul2(di2, acc[j][0]));
        st.y = h2u(__hmul2(di2, acc[j][1]));
        st.z = h2u(__hmul2(di2, acc[j][2]));
        st.w = h2u(__hmul2(di2, acc[j][3]));
        *(uint4v*)(ylds + (rg * 4 + j) * YSTRIDE + (g & 3) * 64 + q * 8) = st;
      }
    }
    float4v acc[4];
#pragma unroll
    for (int t = 0; t < 4; ++t) acc[t] = (float4v){bias[t], bias[t], bias[t], bias[t]};
#pragma unroll
    for (int s2 = 0; s2 < 8; ++s2) {
      half8 af = *(half8*)(ylds + col * YSTRIDE + s2 * 32 + quad * 8);
      const int sW = s2 & 1;
#pragma unroll
      for (int t = 0; t < 4; ++t)
        acc[t] = __builtin_amdgcn_mfma_f32_16x16x32_f16(af, bfrag[sW][t], acc[t], 0, 0, 0);
    }
#pragma unroll
    for (int t = 0; t < 4; ++t)
#pragma unroll
      for (int reg = 0; reg < 4; ++reg) {
        const int row = row0 + quad * 4 + reg;
        if (row < n) {
          const int j = t * 16 + col;
          if (j < 32)
            out_mu[(size_t)row * 32 + j] = acc[t][reg];
          else
            out_lv[(size_t)row * 32 + (j - 32)] = acc[t][reg];
        }
      }
  }
}

extern "C" void kernel_launch(void* const* d_in, const int* in_sizes, int n_in,
                              void* d_out, int out_size, void* d_ws, size_t ws_size,
                              hipStream_t stream) {
  const float* x = (const float*)d_in[0];
  const int* ei = (const int*)d_in[1];  // [2, E] row-major int32
  const float* W1 = (const float*)d_in[2];
  const float* b1 = (const float*)d_in[3];
  const float* Wmu = (const float*)d_in[4];
  const float* bmu = (const float*)d_in[5];
  const float* Wlv = (const float*)d_in[6];
  const float* blv = (const float*)d_in[7];

  const int N = in_sizes[0] / 64;
  const int E = in_sizes[1] / 2;
  const int* src = ei;
  const int* dst = ei + E;

  const int NBK = (N + BKT_NODES - 1) >> BKT_SHIFT;  // 196 buckets (<=256)
  const int NBLK = (E + CHUNK - 1) / CHUNK;          // 391 chunks (<=512)
  const int FL = NBK * NBLK;                         // ~77k

  auto align256 = [](size_t v) { return (v + 255) & ~(size_t)255; };
  char* p = (char*)d_ws;
  int* row_ptr = (int*)p;  p += align256((size_t)(N + 1) * 4);
  float* dinv = (float*)p; p += align256((size_t)N * 4);
  int* rowsum = (int*)p;   p += align256((size_t)256 * 4);
  int* cnt = (int*)p;      p += align256((size_t)FL * 4);
  int* pairs = (int*)p;    p += align256((size_t)E * 4);
  __half* xs = (__half*)p; p += align256((size_t)(N + 1) * 64 * 2);
  size_t tmp_bytes = (size_t)E * 4;  // packed int
  size_t hs_bytes = (size_t)(N + 1) * 64 * 2;
  int* tmp = (int*)p;      // union: tmp dead after bucket_build; hs written later
  __half* hs = (__half*)p;
  p += align256(tmp_bytes > hs_bytes ? tmp_bytes : hs_bytes);

  float* out_mu = (float*)d_out;
  float* out_lv = out_mu + (size_t)N * 32;

  const int n4 = N * 16;

  // --- CSR build: 4 plain dispatches, LDS-staged line-granular writes ---
  bucket_count<<<NBLK, 512, 0, stream>>>(dst, cnt, E, NBK, NBLK);
  scan_rows<<<NBK, 256, 0, stream>>>(cnt, rowsum, NBK, NBLK);
  bucket_scatter<<<NBLK, 512, 0, stream>>>(src, dst, cnt, rowsum, tmp, E, NBK, NBLK);
  bucket_build<<<NBK, 1024, 0, stream>>>(tmp, rowsum, row_ptr, dinv, pairs, N, NBK, E);

  // --- tables (chip-filling standalone cast; after build, hs aliases tmp) ---
  cast_scale<<<(n4 + 32 + 255) / 256, 256, 0, stream>>>(x, dinv, xs, hs, n4, N);

  // --- aggregation + fused dense layers (MFMA epilogue) ---
  const int ntiles = (N + 15) / 16;
  const int ablocks = (ntiles + 3) / 4;  // 1 tile (16 rows) per wave
  agg_layer1<<<ablocks, 256, 0, stream>>>(xs, pairs, row_ptr, W1, b1, hs, N);
  agg_layer2<<<ablocks, 256, 0, stream>>>(hs, pairs, row_ptr, Wmu, bmu, Wlv, blv,
                                          out_mu, out_lv, N);
}